// Round 2
// baseline (93506.921 us; speedup 1.0000x reference)
//
#include <hip/hip_runtime.h>

// ---------- types & helpers ----------
typedef __bf16 bf16x8 __attribute__((ext_vector_type(8)));
typedef float  f32x4  __attribute__((ext_vector_type(4)));

__device__ __forceinline__ float bf2f(unsigned short u) {
  union { unsigned int i; float f; } v; v.i = ((unsigned int)u) << 16; return v.f;
}
__device__ __forceinline__ unsigned short f2bf(float f) {
  union { float f; unsigned int u; } v; v.f = f;
  unsigned int r = v.u + 0x7fffu + ((v.u >> 16) & 1u);
  return (unsigned short)(r >> 16);
}
__device__ __forceinline__ float sigm(float x)   { return 1.f / (1.f + __expf(-x)); }
__device__ __forceinline__ float tanh_f(float x) { return 2.f / (1.f + __expf(-2.f * x)) - 1.f; }
__device__ __forceinline__ bf16x8 ld8(const unsigned short* p) {
  return *reinterpret_cast<const bf16x8*>(p);
}

// ---------- fp32 -> bf16 bulk convert (weights & x), once per launch ----------
__global__ __launch_bounds__(256) void f32_to_bf16(const float* __restrict__ src,
                                                   unsigned short* __restrict__ dst, int n4) {
  int i = blockIdx.x * blockDim.x + threadIdx.x;
  const int stride = gridDim.x * blockDim.x;
  const float4* s4 = (const float4*)src;
  ushort4* d4 = (ushort4*)dst;
  for (; i < n4; i += stride) {
    float4 v = s4[i];
    ushort4 o;
    o.x = f2bf(v.x); o.y = f2bf(v.y); o.z = f2bf(v.z); o.w = f2bf(v.w);
    d4[i] = o;
  }
}

// ---------- grid barrier (monotonic counter; device-scope; XCD-safe) ----------
#define G_BLOCKS 256
__device__ __forceinline__ void gbar(unsigned* bar, unsigned target) {
  __syncthreads();
  if (threadIdx.x == 0) {
    __threadfence();                 // release: drain my writes to coherent point
    atomicAdd(bar, 1u);              // device-scope by default
    while (__hip_atomic_load(bar, __ATOMIC_RELAXED, __HIP_MEMORY_SCOPE_AGENT) < target) {
      __builtin_amdgcn_s_sleep(1);
    }
    __threadfence();                 // acquire: invalidate stale caches
  }
  __syncthreads();
}

// accumulate one quarter (kq) of a K-segment into 4 gate accumulators.
template<int C>
__device__ __forceinline__ void seg_quarter(f32x4 acc[4],
    const unsigned short* __restrict__ a, int astride,
    const unsigned short* __restrict__ w, int wstride,
    int m0, int j0, int quad, int col, int kq)
{
  constexpr int CQ = C / 4;
  const unsigned short* ar = a + (size_t)(m0 + col) * astride + quad * 8 + kq * CQ * 32;
  const unsigned short* wr = w + quad * 8 + kq * CQ * 32;
#pragma unroll
  for (int c = 0; c < CQ; c++) {
    bf16x8 af = ld8(ar + c * 32);
#pragma unroll
    for (int g = 0; g < 4; g++) {
      acc[g] = __builtin_amdgcn_mfma_f32_16x16x32_bf16(
          af, ld8(wr + (size_t)(g * 128 + j0 + col) * wstride + c * 32),
          acc[g], 0, 0, 0);
    }
  }
}

// ---------- stage: standard LSTM cell (adapt cells). 32 blocks x 4 waves ----------
// blk: j0 = (blk>>2)*16, m0 = (blk&3)*16 ; wave = k-quarter.
template<int C0, int C1, int C2, int C3>
__device__ void st_adapt(int blk,
    const unsigned short* __restrict__ a0, int as0, const unsigned short* __restrict__ w0, int ws0,
    const unsigned short* __restrict__ a1, int as1, const unsigned short* __restrict__ w1, int ws1,
    const unsigned short* __restrict__ a2, int as2, const unsigned short* __restrict__ w2, int ws2,
    const unsigned short* __restrict__ a3, int as3, const unsigned short* __restrict__ w3, int ws3,
    const float* __restrict__ bih, const float* __restrict__ bhh,
    float* __restrict__ cbuf, unsigned short* __restrict__ hbuf)
{
  const int tid = threadIdx.x;
  const int kq = tid >> 6, lane = tid & 63;
  const int quad = lane >> 4, col = lane & 15;
  const int m0 = (blk & 3) * 16, j0 = (blk >> 2) * 16;

  f32x4 acc[4] = {};
  seg_quarter<C0>(acc, a0, as0, w0, ws0, m0, j0, quad, col, kq);
  seg_quarter<C1>(acc, a1, as1, w1, ws1, m0, j0, quad, col, kq);
  seg_quarter<C2>(acc, a2, as2, w2, ws2, m0, j0, quad, col, kq);
  seg_quarter<C3>(acc, a3, as3, w3, ws3, m0, j0, quad, col, kq);

  __shared__ f32x4 red_a[3][4][64];
  if (kq) {
#pragma unroll
    for (int g = 0; g < 4; g++) red_a[kq - 1][g][lane] = acc[g];
  }
  __syncthreads();
  if (kq == 0) {
#pragma unroll
    for (int p = 0; p < 3; p++)
#pragma unroll
      for (int g = 0; g < 4; g++) acc[g] += red_a[p][g][lane];

    const int j = j0 + col;
    const float b0 = bih[j]       + bhh[j];
    const float b1 = bih[128 + j] + bhh[128 + j];
    const float b2 = bih[256 + j] + bhh[256 + j];
    const float b3 = bih[384 + j] + bhh[384 + j];
#pragma unroll
    for (int r = 0; r < 4; r++) {
      const int m = m0 + quad * 4 + r;
      const float i_ = sigm(acc[0][r] + b0);
      const float f_ = sigm(acc[1][r] + b1);
      const float g_ = tanh_f(acc[2][r] + b2);
      const float o_ = sigm(acc[3][r] + b3);
      const int idx = m * 128 + j;
      const float c2 = f_ * cbuf[idx] + i_ * g_;
      cbuf[idx] = c2;
      hbuf[idx] = f2bf(o_ * tanh_f(c2));
    }
  }
}

// ---------- stage: x-hat / h-hat production. N/64 blocks x 4 waves ----------
__device__ void st_policy(int blk,
    const unsigned short* __restrict__ A,    // 64 x 128 bf16 (adapt hx, current step)
    const unsigned short* __restrict__ pw,   // policy weights rows [0, xn+hn)
    const float* __restrict__ pb,
    const unsigned short* __restrict__ xsrc, int xn,
    const unsigned short* __restrict__ hsrc, int hn,
    unsigned short* __restrict__ xhat, unsigned short* __restrict__ hhat)
{
  const int wave = threadIdx.x >> 6, lane = threadIdx.x & 63;
  const int quad = lane >> 4, col = lane & 15;
  const int m0 = wave * 16, n0 = blk * 64;

  f32x4 acc[4] = {};
  const unsigned short* arow = A + (size_t)(m0 + col) * 128 + quad * 8;
#pragma unroll
  for (int c = 0; c < 4; c++) {
    bf16x8 af = ld8(arow + c * 32);
#pragma unroll
    for (int s = 0; s < 4; s++) {
      acc[s] = __builtin_amdgcn_mfma_f32_16x16x32_bf16(
          af, ld8(pw + (size_t)(n0 + s * 16 + col) * 128 + quad * 8 + c * 32),
          acc[s], 0, 0, 0);
    }
  }
#pragma unroll
  for (int s = 0; s < 4; s++) {
    const int n = n0 + s * 16 + col;
    const float bias = pb[n];
#pragma unroll
    for (int r = 0; r < 4; r++) {
      const int m = m0 + quad * 4 + r;
      const float v = acc[s][r] + bias;
      if (n < xn) {
        xhat[m * xn + n] = f2bf(v * bf2f(xsrc[m * xn + n]));
      } else {
        hhat[m * hn + (n - xn)] = f2bf(v * bf2f(hsrc[m * hn + (n - xn)]));
      }
    }
  }
}

// ---------- stage: adaptive LSTM cell (f cells). 128 blocks x 4 waves ----------
// blk: j0 = (blk>>1)*16, mpair = blk&1 ; wave: mw = wave>>1, kh = wave&1.
// Policy gate-scale slices: kh0 computes ig/hg sets, kh1 computes ab set (passed via LDS).
template<int XK, int HK>
__device__ void st_fcell(int blk,
    const unsigned short* __restrict__ xhat,  // 64 x XK bf16
    const unsigned short* __restrict__ hhat,  // 64 x HK bf16
    const unsigned short* __restrict__ wih,   // 4096 x XK bf16
    const unsigned short* __restrict__ whh,   // 4096 x HK bf16
    const float* __restrict__ fb,             // 4096 fp32
    const unsigned short* __restrict__ ax,    // 64 x 128 bf16 (adapt hx, current step)
    const unsigned short* __restrict__ pw,    // policy weights (full)
    const float* __restrict__ pb,             // policy bias (full)
    int ig_off, int hg_off, int ab_off,
    float* __restrict__ cbuf, unsigned short* __restrict__ hbuf, float* __restrict__ outp)
{
  const int tid = threadIdx.x;
  const int wave = tid >> 6, lane = tid & 63;
  const int mw = wave >> 1, kh = wave & 1;
  const int quad = lane >> 4, col = lane & 15;
  const int j0 = (blk >> 1) * 16;
  const int m0 = ((blk & 1) * 2 + mw) * 16;
  constexpr int XC = XK / 32, HC = HK / 32;

  __shared__ f32x4 redA[2][8][64];
  __shared__ f32x4 redP[2][4][64];

  // policy slices first so their loads overlap the main GEMM
  f32x4 pg0[4] = {}, pg1[4] = {}, pg2[4] = {};
  {
    const unsigned short* ar = ax + (size_t)(m0 + col) * 128 + quad * 8;
    if (kh == 0) {
#pragma unroll
      for (int c = 0; c < 4; c++) {
        bf16x8 af = ld8(ar + c * 32);
#pragma unroll
        for (int g = 0; g < 4; g++) {
          pg0[g] = __builtin_amdgcn_mfma_f32_16x16x32_bf16(
              af, ld8(pw + (size_t)(ig_off + g * 1024 + j0 + col) * 128 + quad * 8 + c * 32), pg0[g], 0, 0, 0);
          pg1[g] = __builtin_amdgcn_mfma_f32_16x16x32_bf16(
              af, ld8(pw + (size_t)(hg_off + g * 1024 + j0 + col) * 128 + quad * 8 + c * 32), pg1[g], 0, 0, 0);
        }
      }
    } else {
#pragma unroll
      for (int c = 0; c < 4; c++) {
        bf16x8 af = ld8(ar + c * 32);
#pragma unroll
        for (int g = 0; g < 4; g++) {
          pg2[g] = __builtin_amdgcn_mfma_f32_16x16x32_bf16(
              af, ld8(pw + (size_t)(ab_off + g * 1024 + j0 + col) * 128 + quad * 8 + c * 32), pg2[g], 0, 0, 0);
        }
      }
    }
  }

  f32x4 ig[4] = {}, hg[4] = {};
  {
    const unsigned short* ar = xhat + (size_t)(m0 + col) * XK + quad * 8 + kh * (XC / 2) * 32;
    const unsigned short* wr = wih + quad * 8 + kh * (XC / 2) * 32;
#pragma unroll
    for (int c = 0; c < XC / 2; c++) {
      bf16x8 af = ld8(ar + c * 32);
#pragma unroll
      for (int g = 0; g < 4; g++) {
        ig[g] = __builtin_amdgcn_mfma_f32_16x16x32_bf16(
            af, ld8(wr + (size_t)(g * 1024 + j0 + col) * XK + c * 32), ig[g], 0, 0, 0);
      }
    }
  }
  {
    const unsigned short* ar = hhat + (size_t)(m0 + col) * HK + quad * 8 + kh * (HC / 2) * 32;
    const unsigned short* wr = whh + quad * 8 + kh * (HC / 2) * 32;
#pragma unroll
    for (int c = 0; c < HC / 2; c++) {
      bf16x8 af = ld8(ar + c * 32);
#pragma unroll
      for (int g = 0; g < 4; g++) {
        hg[g] = __builtin_amdgcn_mfma_f32_16x16x32_bf16(
            af, ld8(wr + (size_t)(g * 1024 + j0 + col) * HK + c * 32), hg[g], 0, 0, 0);
      }
    }
  }

  if (kh == 1) {
#pragma unroll
    for (int g = 0; g < 4; g++) {
      redA[mw][g][lane] = ig[g];
      redA[mw][4 + g][lane] = hg[g];
      redP[mw][g][lane] = pg2[g];
    }
  }
  __syncthreads();
  if (kh == 0) {
#pragma unroll
    for (int g = 0; g < 4; g++) { ig[g] += redA[mw][g][lane]; hg[g] += redA[mw][4 + g][lane]; }

    const int j = j0 + col;
    float pb0[4], pb1[4], pb2[4], fbv[4];
#pragma unroll
    for (int g = 0; g < 4; g++) {
      pb0[g] = pb[ig_off + g * 1024 + j];
      pb1[g] = pb[hg_off + g * 1024 + j];
      pb2[g] = pb[ab_off + g * 1024 + j];
      fbv[g] = fb[g * 1024 + j];
    }
#pragma unroll
    for (int r = 0; r < 4; r++) {
      const int m = m0 + quad * 4 + r;
      float gate[4];
#pragma unroll
      for (int g = 0; g < 4; g++) {
        gate[g] = ig[g][r] * (pg0[g][r] + pb0[g])
                + hg[g][r] * (pg1[g][r] + pb1[g])
                + fbv[g]   * (redP[mw][g][lane][r] + pb2[g]);
      }
      const float i_ = sigm(gate[0]);
      const float f_ = sigm(gate[1]);
      const float g_ = tanh_f(gate[2]);
      const float o_ = sigm(gate[3]);
      const int idx = m * 1024 + j;
      const float c2 = f_ * cbuf[idx] + i_ * g_;
      cbuf[idx] = c2;
      const float h = o_ * tanh_f(c2);
      hbuf[idx] = f2bf(h);
      if (outp) outp[idx] = h;
    }
  }
}

// ---------- the persistent kernel: all 512 steps, 4 barrier slots per step ----------
// Steady-state schedule (cycle t): A:{S3(t)} B:{S4(t)} C:{S5(t) || S1(t+1)} D:{S6(t) || S2(t+1)}
__global__ __launch_bounds__(256, 3) void alstm_persistent(
    const unsigned short* __restrict__ xb, float* __restrict__ out,
    const unsigned short* __restrict__ a_wih0b, const unsigned short* __restrict__ a_whh0b,
    const float* __restrict__ a_bih0, const float* __restrict__ a_bhh0,
    const unsigned short* __restrict__ p_w0b, const float* __restrict__ p_b0,
    const unsigned short* __restrict__ f_wih0b, const unsigned short* __restrict__ f_whh0b,
    const float* __restrict__ f_b0,
    const unsigned short* __restrict__ a_wih1b, const unsigned short* __restrict__ a_whh1b,
    const float* __restrict__ a_bih1, const float* __restrict__ a_bhh1,
    const unsigned short* __restrict__ p_w1b, const float* __restrict__ p_b1,
    const unsigned short* __restrict__ f_wih1b, const unsigned short* __restrict__ f_whh1b,
    const float* __restrict__ f_b1,
    float* a0c, float* a1c, float* f0c, float* f1c,
    unsigned short* a0xA, unsigned short* a0xB,
    unsigned short* a1xA, unsigned short* a1xB,
    unsigned short* f0x, unsigned short* f1x,
    unsigned short* xh0, unsigned short* hh0,
    unsigned short* xh1, unsigned short* hh1,
    unsigned* bar)
{
  const int blk = blockIdx.x;
  unsigned ep = 0;

  // prologue: S1(0) then S2(0)
  if (blk >= 32 && blk < 64)
    st_adapt<8, 32, 4, 4>(blk - 32,
        xb, 256, a_wih0b, 1408,
        f0x, 1024, a_wih0b + 256, 1408,
        a1xB, 128, a_wih0b + 1280, 1408,
        a0xB, 128, a_whh0b, 128,
        a_bih0, a_bhh0, a0c, a0xA);
  gbar(bar, ++ep * (unsigned)G_BLOCKS);
  if (blk >= 128 && blk < 148)
    st_policy(blk - 128, a0xA, p_w0b, p_b0, xb, 256, f0x, 1024, xh0, hh0);
  gbar(bar, ++ep * (unsigned)G_BLOCKS);

#pragma unroll 1
  for (int t = 0; t < 512; t++) {
    const unsigned short* xt1 = xb + (size_t)(t + 1) * 64 * 256;
    unsigned short* a0x_cur  = (t & 1) ? a0xB : a0xA;
    unsigned short* a0x_nxt  = (t & 1) ? a0xA : a0xB;
    unsigned short* a1x_cur  = (t & 1) ? a1xB : a1xA;
    unsigned short* a1x_prev = (t & 1) ? a1xA : a1xB;
    const bool more = (t + 1 < 512);

    // slot A: S3(t) = f-cell 0
    if (blk < 128)
      st_fcell<256, 1024>(blk, xh0, hh0, f_wih0b, f_whh0b, f_b0,
                          a0x_cur, p_w0b, p_b0, 1280, 5376, 9472,
                          f0c, f0x, (float*)nullptr);
    gbar(bar, ++ep * (unsigned)G_BLOCKS);

    // slot B: S4(t) = adapt cell 1
    if (blk < 32)
      st_adapt<32, 32, 4, 4>(blk,
          f0x, 1024, a_wih1b, 2176,
          f1x, 1024, a_wih1b + 1024, 2176,
          a0x_cur, 128, a_wih1b + 2048, 2176,
          a1x_prev, 128, a_whh1b, 128,
          a_bih1, a_bhh1, a1c, a1x_cur);
    gbar(bar, ++ep * (unsigned)G_BLOCKS);

    // slot C: S5(t) = policy 1  ||  S1(t+1) = adapt cell 0
    if (blk < 32)
      st_policy(blk, a1x_cur, p_w1b, p_b1, f0x, 1024, f1x, 1024, xh1, hh1);
    else if (blk < 64 && more)
      st_adapt<8, 32, 4, 4>(blk - 32,
          xt1, 256, a_wih0b, 1408,
          f0x, 1024, a_wih0b + 256, 1408,
          a1x_cur, 128, a_wih0b + 1280, 1408,
          a0x_cur, 128, a_whh0b, 128,
          a_bih0, a_bhh0, a0c, a0x_nxt);
    gbar(bar, ++ep * (unsigned)G_BLOCKS);

    // slot D: S6(t) = f-cell 1  ||  S2(t+1) = policy 0
    if (blk < 128)
      st_fcell<1024, 1024>(blk, xh1, hh1, f_wih1b, f_whh1b, f_b1,
                           a1x_cur, p_w1b, p_b1, 2048, 6144, 10240,
                           f1c, f1x, out + (size_t)t * 64 * 1024);
    else if (blk < 148 && more)
      st_policy(blk - 128, a0x_nxt, p_w0b, p_b0, xt1, 256, f0x, 1024, xh0, hh0);
    gbar(bar, ++ep * (unsigned)G_BLOCKS);
  }
}

extern "C" void kernel_launch(void* const* d_in, const int* in_sizes, int n_in,
                              void* d_out, int out_size, void* d_ws, size_t ws_size,
                              hipStream_t stream)
{
  const float* x      = (const float*)d_in[0];
  const float* a_wih0 = (const float*)d_in[1];
  const float* a_whh0 = (const float*)d_in[2];
  const float* a_bih0 = (const float*)d_in[3];
  const float* a_bhh0 = (const float*)d_in[4];
  const float* p_w0   = (const float*)d_in[5];
  const float* p_b0   = (const float*)d_in[6];
  const float* f_wih0 = (const float*)d_in[7];
  const float* f_whh0 = (const float*)d_in[8];
  const float* f_b0   = (const float*)d_in[9];
  const float* a_wih1 = (const float*)d_in[10];
  const float* a_whh1 = (const float*)d_in[11];
  const float* a_bih1 = (const float*)d_in[12];
  const float* a_bhh1 = (const float*)d_in[13];
  const float* p_w1   = (const float*)d_in[14];
  const float* p_b1   = (const float*)d_in[15];
  const float* f_wih1 = (const float*)d_in[16];
  const float* f_whh1 = (const float*)d_in[17];
  const float* f_b1   = (const float*)d_in[18];
  float* out = (float*)d_out;

  // ---- workspace carve-up (256B-aligned cursor) ----
  char* p = (char*)d_ws;
  auto alloc = [&](size_t bytes) { char* r = p; p += (bytes + 255) & ~(size_t)255; return r; };

  // zeroed each launch: barrier counter + recurrent state
  unsigned* bar = (unsigned*)alloc(256);
  float* a0c = (float*)alloc(64 * 128 * 4);
  float* a1c = (float*)alloc(64 * 128 * 4);
  float* f0c = (float*)alloc(64 * 1024 * 4);
  float* f1c = (float*)alloc(64 * 1024 * 4);
  unsigned short* a0xA = (unsigned short*)alloc(64 * 128 * 2);
  unsigned short* a0xB = (unsigned short*)alloc(64 * 128 * 2);
  unsigned short* a1xA = (unsigned short*)alloc(64 * 128 * 2);
  unsigned short* a1xB = (unsigned short*)alloc(64 * 128 * 2);
  unsigned short* f0x  = (unsigned short*)alloc(64 * 1024 * 2);
  unsigned short* f1x  = (unsigned short*)alloc(64 * 1024 * 2);
  const size_t zero_bytes = (size_t)(p - (char*)d_ws);

  // per-step scratch (fully written before read each step)
  unsigned short* xh0 = (unsigned short*)alloc(64 * 256 * 2);
  unsigned short* hh0 = (unsigned short*)alloc(64 * 1024 * 2);
  unsigned short* xh1 = (unsigned short*)alloc(64 * 1024 * 2);
  unsigned short* hh1 = (unsigned short*)alloc(64 * 1024 * 2);

  // bf16 conversions of x + weights
  unsigned short* xb      = (unsigned short*)alloc((size_t)8388608 * 2);
  unsigned short* a_wih0b = (unsigned short*)alloc((size_t)720896 * 2);
  unsigned short* a_whh0b = (unsigned short*)alloc((size_t)65536 * 2);
  unsigned short* p_w0b   = (unsigned short*)alloc((size_t)1736704 * 2);
  unsigned short* f_wih0b = (unsigned short*)alloc((size_t)1048576 * 2);
  unsigned short* f_whh0b = (unsigned short*)alloc((size_t)4194304 * 2);
  unsigned short* a_wih1b = (unsigned short*)alloc((size_t)1114112 * 2);
  unsigned short* a_whh1b = (unsigned short*)alloc((size_t)65536 * 2);
  unsigned short* p_w1b   = (unsigned short*)alloc((size_t)1835008 * 2);
  unsigned short* f_wih1b = (unsigned short*)alloc((size_t)4194304 * 2);
  unsigned short* f_whh1b = (unsigned short*)alloc((size_t)4194304 * 2);

  hipMemsetAsync(d_ws, 0, zero_bytes, stream);

  auto conv = [&](const float* s, unsigned short* d, size_t n) {
    int n4 = (int)(n >> 2);
    int blocks = (n4 + 255) / 256; if (blocks > 1024) blocks = 1024;
    f32_to_bf16<<<blocks, 256, 0, stream>>>(s, d, n4);
  };
  conv(x,      xb,      8388608);
  conv(a_wih0, a_wih0b, 720896);
  conv(a_whh0, a_whh0b, 65536);
  conv(p_w0,   p_w0b,   1736704);
  conv(f_wih0, f_wih0b, 1048576);
  conv(f_whh0, f_whh0b, 4194304);
  conv(a_wih1, a_wih1b, 1114112);
  conv(a_whh1, a_whh1b, 65536);
  conv(p_w1,   p_w1b,   1835008);
  conv(f_wih1, f_wih1b, 4194304);
  conv(f_whh1, f_whh1b, 4194304);

  alstm_persistent<<<G_BLOCKS, 256, 0, stream>>>(
      xb, out,
      a_wih0b, a_whh0b, a_bih0, a_bhh0, p_w0b, p_b0, f_wih0b, f_whh0b, f_b0,
      a_wih1b, a_whh1b, a_bih1, a_bhh1, p_w1b, p_b1, f_wih1b, f_whh1b, f_b1,
      a0c, a1c, f0c, f1c, a0xA, a0xB, a1xA, a1xB, f0x, f1x,
      xh0, hh0, xh1, hh1, bar);
}

// Round 3
// 74408.685 us; speedup vs baseline: 1.2567x; 1.2567x over previous
//
#include <hip/hip_runtime.h>

// ---------- types & helpers ----------
typedef __bf16 bf16x8 __attribute__((ext_vector_type(8)));
typedef float  f32x4  __attribute__((ext_vector_type(4)));

#define AS __HIP_MEMORY_SCOPE_AGENT

__device__ __forceinline__ float bf2f(unsigned short u) {
  union { unsigned int i; float f; } v; v.i = ((unsigned int)u) << 16; return v.f;
}
__device__ __forceinline__ unsigned short f2bf(float f) {
  union { float f; unsigned int u; } v; v.f = f;
  unsigned int r = v.u + 0x7fffu + ((v.u >> 16) & 1u);
  return (unsigned short)(r >> 16);
}
__device__ __forceinline__ float sigm(float x)   { return 1.f / (1.f + __expf(-x)); }
__device__ __forceinline__ float tanh_f(float x) { return 2.f / (1.f + __expf(-2.f * x)) - 1.f; }

// cached load (weights / immutable data only)
__device__ __forceinline__ bf16x8 ld8(const unsigned short* p) {
  return *reinterpret_cast<const bf16x8*>(p);
}
// coherent (agent-scope, L2-bypassing) accessors for cross-block mutable buffers.
// Relaxed atomic load/store at agent scope emits sc0/sc1 flags: always-fresh, no fences.
__device__ __forceinline__ bf16x8 ldc8(const unsigned short* p) {
  const unsigned* q = (const unsigned*)p;
  union { unsigned u[4]; bf16x8 v; } r;
  r.u[0] = __hip_atomic_load(q + 0, __ATOMIC_RELAXED, AS);
  r.u[1] = __hip_atomic_load(q + 1, __ATOMIC_RELAXED, AS);
  r.u[2] = __hip_atomic_load(q + 2, __ATOMIC_RELAXED, AS);
  r.u[3] = __hip_atomic_load(q + 3, __ATOMIC_RELAXED, AS);
  return r.v;
}
__device__ __forceinline__ unsigned short ldc_bf(const unsigned short* p) {
  return __hip_atomic_load(p, __ATOMIC_RELAXED, AS);
}
__device__ __forceinline__ void stc_bf(unsigned short* p, unsigned short v) {
  __hip_atomic_store(p, v, __ATOMIC_RELAXED, AS);
}

// ---------- fp32 -> bf16 bulk convert (weights & x), once per launch ----------
__global__ __launch_bounds__(256) void f32_to_bf16(const float* __restrict__ src,
                                                   unsigned short* __restrict__ dst, int n4) {
  int i = blockIdx.x * blockDim.x + threadIdx.x;
  const int stride = gridDim.x * blockDim.x;
  const float4* s4 = (const float4*)src;
  ushort4* d4 = (ushort4*)dst;
  for (; i < n4; i += stride) {
    float4 v = s4[i];
    ushort4 o;
    o.x = f2bf(v.x); o.y = f2bf(v.y); o.z = f2bf(v.z); o.w = f2bf(v.w);
    d4[i] = o;
  }
}

// ---------- grid barrier: NO cache invalidation ----------
// All cross-block data moves via agent-scope (sc0/sc1) accesses, so the barrier only
// needs: drain my stores (vmcnt via syncthreads' waitcnt + explicit), bump counter,
// spin. L2 keeps weights resident across all 512 steps.
#define G_BLOCKS 256
__device__ __forceinline__ void gbar(unsigned* bar, unsigned target) {
  asm volatile("s_waitcnt vmcnt(0)" ::: "memory");
  __syncthreads();
  if (threadIdx.x == 0) {
    __hip_atomic_fetch_add(bar, 1u, __ATOMIC_RELAXED, AS);
    while (__hip_atomic_load(bar, __ATOMIC_RELAXED, AS) < target) {
      __builtin_amdgcn_s_sleep(2);
    }
  }
  __syncthreads();
  asm volatile("" ::: "memory");
}

// accumulate one quarter (kq) of a K-segment into 4 gate accumulators.
// A-operand is cross-block mutable -> coherent loads; weights cached.
template<int C>
__device__ __forceinline__ void seg_quarter(f32x4 acc[4],
    const unsigned short* __restrict__ a, int astride,
    const unsigned short* __restrict__ w, int wstride,
    int m0, int j0, int quad, int col, int kq)
{
  constexpr int CQ = C / 4;
  const unsigned short* ar = a + (size_t)(m0 + col) * astride + quad * 8 + kq * CQ * 32;
  const unsigned short* wr = w + quad * 8 + kq * CQ * 32;
#pragma unroll
  for (int c = 0; c < CQ; c++) {
    bf16x8 af = ldc8(ar + c * 32);
#pragma unroll
    for (int g = 0; g < 4; g++) {
      acc[g] = __builtin_amdgcn_mfma_f32_16x16x32_bf16(
          af, ld8(wr + (size_t)(g * 128 + j0 + col) * wstride + c * 32),
          acc[g], 0, 0, 0);
    }
  }
}

// ---------- stage: standard LSTM cell (adapt cells). 32 blocks x 4 waves ----------
template<int C0, int C1, int C2, int C3>
__device__ void st_adapt(int blk,
    const unsigned short* __restrict__ a0, int as0, const unsigned short* __restrict__ w0, int ws0,
    const unsigned short* __restrict__ a1, int as1, const unsigned short* __restrict__ w1, int ws1,
    const unsigned short* __restrict__ a2, int as2, const unsigned short* __restrict__ w2, int ws2,
    const unsigned short* __restrict__ a3, int as3, const unsigned short* __restrict__ w3, int ws3,
    const float* __restrict__ bih, const float* __restrict__ bhh,
    float* __restrict__ cbuf, unsigned short* __restrict__ hbuf)
{
  const int tid = threadIdx.x;
  const int kq = tid >> 6, lane = tid & 63;
  const int quad = lane >> 4, col = lane & 15;
  const int m0 = (blk & 3) * 16, j0 = (blk >> 2) * 16;

  f32x4 acc[4] = {};
  seg_quarter<C0>(acc, a0, as0, w0, ws0, m0, j0, quad, col, kq);
  seg_quarter<C1>(acc, a1, as1, w1, ws1, m0, j0, quad, col, kq);
  seg_quarter<C2>(acc, a2, as2, w2, ws2, m0, j0, quad, col, kq);
  seg_quarter<C3>(acc, a3, as3, w3, ws3, m0, j0, quad, col, kq);

  __shared__ f32x4 red_a[3][4][64];
  if (kq) {
#pragma unroll
    for (int g = 0; g < 4; g++) red_a[kq - 1][g][lane] = acc[g];
  }
  __syncthreads();
  if (kq == 0) {
#pragma unroll
    for (int p = 0; p < 3; p++)
#pragma unroll
      for (int g = 0; g < 4; g++) acc[g] += red_a[p][g][lane];

    const int j = j0 + col;
    const float b0 = bih[j]       + bhh[j];
    const float b1 = bih[128 + j] + bhh[128 + j];
    const float b2 = bih[256 + j] + bhh[256 + j];
    const float b3 = bih[384 + j] + bhh[384 + j];
#pragma unroll
    for (int r = 0; r < 4; r++) {
      const int m = m0 + quad * 4 + r;
      const float i_ = sigm(acc[0][r] + b0);
      const float f_ = sigm(acc[1][r] + b1);
      const float g_ = tanh_f(acc[2][r] + b2);
      const float o_ = sigm(acc[3][r] + b3);
      const int idx = m * 128 + j;
      const float c2 = f_ * cbuf[idx] + i_ * g_;   // c-state: block-private, cached
      cbuf[idx] = c2;
      stc_bf(&hbuf[idx], f2bf(o_ * tanh_f(c2)));   // h: cross-block -> coherent
    }
  }
}

// ---------- stage: x-hat / h-hat production. N/64 blocks x 4 waves ----------
__device__ void st_policy(int blk,
    const unsigned short* __restrict__ A,    // 64 x 128 bf16 (adapt hx, current step)
    const unsigned short* __restrict__ pw,   // policy weights rows [0, xn+hn)
    const float* __restrict__ pb,
    const unsigned short* __restrict__ xsrc, int xn,
    const unsigned short* __restrict__ hsrc, int hn,
    unsigned short* __restrict__ xhat, unsigned short* __restrict__ hhat)
{
  const int wave = threadIdx.x >> 6, lane = threadIdx.x & 63;
  const int quad = lane >> 4, col = lane & 15;
  const int m0 = wave * 16, n0 = blk * 64;

  f32x4 acc[4] = {};
  const unsigned short* arow = A + (size_t)(m0 + col) * 128 + quad * 8;
#pragma unroll
  for (int c = 0; c < 4; c++) {
    bf16x8 af = ldc8(arow + c * 32);
#pragma unroll
    for (int s = 0; s < 4; s++) {
      acc[s] = __builtin_amdgcn_mfma_f32_16x16x32_bf16(
          af, ld8(pw + (size_t)(n0 + s * 16 + col) * 128 + quad * 8 + c * 32),
          acc[s], 0, 0, 0);
    }
  }
#pragma unroll
  for (int s = 0; s < 4; s++) {
    const int n = n0 + s * 16 + col;
    const float bias = pb[n];
#pragma unroll
    for (int r = 0; r < 4; r++) {
      const int m = m0 + quad * 4 + r;
      const float v = acc[s][r] + bias;
      if (n < xn) {
        stc_bf(&xhat[m * xn + n], f2bf(v * bf2f(ldc_bf(&xsrc[m * xn + n]))));
      } else {
        stc_bf(&hhat[m * hn + (n - xn)], f2bf(v * bf2f(ldc_bf(&hsrc[m * hn + (n - xn)]))));
      }
    }
  }
}

// ---------- stage: adaptive LSTM cell (f cells). 128 blocks x 4 waves ----------
template<int XK, int HK>
__device__ void st_fcell(int blk,
    const unsigned short* __restrict__ xhat,  // 64 x XK bf16
    const unsigned short* __restrict__ hhat,  // 64 x HK bf16
    const unsigned short* __restrict__ wih,   // 4096 x XK bf16
    const unsigned short* __restrict__ whh,   // 4096 x HK bf16
    const float* __restrict__ fb,             // 4096 fp32
    const unsigned short* __restrict__ ax,    // 64 x 128 bf16 (adapt hx, current step)
    const unsigned short* __restrict__ pw,    // policy weights (full)
    const float* __restrict__ pb,             // policy bias (full)
    int ig_off, int hg_off, int ab_off,
    float* __restrict__ cbuf, unsigned short* __restrict__ hbuf, float* __restrict__ outp)
{
  const int tid = threadIdx.x;
  const int wave = tid >> 6, lane = tid & 63;
  const int mw = wave >> 1, kh = wave & 1;
  const int quad = lane >> 4, col = lane & 15;
  const int j0 = (blk >> 1) * 16;
  const int m0 = ((blk & 1) * 2 + mw) * 16;
  constexpr int XC = XK / 32, HC = HK / 32;

  __shared__ f32x4 redA[2][8][64];
  __shared__ f32x4 redP[2][4][64];

  // policy slices first so their loads overlap the main GEMM
  f32x4 pg0[4] = {}, pg1[4] = {}, pg2[4] = {};
  {
    const unsigned short* ar = ax + (size_t)(m0 + col) * 128 + quad * 8;
    if (kh == 0) {
#pragma unroll
      for (int c = 0; c < 4; c++) {
        bf16x8 af = ldc8(ar + c * 32);
#pragma unroll
        for (int g = 0; g < 4; g++) {
          pg0[g] = __builtin_amdgcn_mfma_f32_16x16x32_bf16(
              af, ld8(pw + (size_t)(ig_off + g * 1024 + j0 + col) * 128 + quad * 8 + c * 32), pg0[g], 0, 0, 0);
          pg1[g] = __builtin_amdgcn_mfma_f32_16x16x32_bf16(
              af, ld8(pw + (size_t)(hg_off + g * 1024 + j0 + col) * 128 + quad * 8 + c * 32), pg1[g], 0, 0, 0);
        }
      }
    } else {
#pragma unroll
      for (int c = 0; c < 4; c++) {
        bf16x8 af = ldc8(ar + c * 32);
#pragma unroll
        for (int g = 0; g < 4; g++) {
          pg2[g] = __builtin_amdgcn_mfma_f32_16x16x32_bf16(
              af, ld8(pw + (size_t)(ab_off + g * 1024 + j0 + col) * 128 + quad * 8 + c * 32), pg2[g], 0, 0, 0);
        }
      }
    }
  }

  f32x4 ig[4] = {}, hg[4] = {};
  {
    const unsigned short* ar = xhat + (size_t)(m0 + col) * XK + quad * 8 + kh * (XC / 2) * 32;
    const unsigned short* wr = wih + quad * 8 + kh * (XC / 2) * 32;
#pragma unroll
    for (int c = 0; c < XC / 2; c++) {
      bf16x8 af = ldc8(ar + c * 32);
#pragma unroll
      for (int g = 0; g < 4; g++) {
        ig[g] = __builtin_amdgcn_mfma_f32_16x16x32_bf16(
            af, ld8(wr + (size_t)(g * 1024 + j0 + col) * XK + c * 32), ig[g], 0, 0, 0);
      }
    }
  }
  {
    const unsigned short* ar = hhat + (size_t)(m0 + col) * HK + quad * 8 + kh * (HC / 2) * 32;
    const unsigned short* wr = whh + quad * 8 + kh * (HC / 2) * 32;
#pragma unroll
    for (int c = 0; c < HC / 2; c++) {
      bf16x8 af = ldc8(ar + c * 32);
#pragma unroll
      for (int g = 0; g < 4; g++) {
        hg[g] = __builtin_amdgcn_mfma_f32_16x16x32_bf16(
            af, ld8(wr + (size_t)(g * 1024 + j0 + col) * HK + c * 32), hg[g], 0, 0, 0);
      }
    }
  }

  if (kh == 1) {
#pragma unroll
    for (int g = 0; g < 4; g++) {
      redA[mw][g][lane] = ig[g];
      redA[mw][4 + g][lane] = hg[g];
      redP[mw][g][lane] = pg2[g];
    }
  }
  __syncthreads();
  if (kh == 0) {
#pragma unroll
    for (int g = 0; g < 4; g++) { ig[g] += redA[mw][g][lane]; hg[g] += redA[mw][4 + g][lane]; }

    const int j = j0 + col;
    float pb0[4], pb1[4], pb2[4], fbv[4];
#pragma unroll
    for (int g = 0; g < 4; g++) {
      pb0[g] = pb[ig_off + g * 1024 + j];
      pb1[g] = pb[hg_off + g * 1024 + j];
      pb2[g] = pb[ab_off + g * 1024 + j];
      fbv[g] = fb[g * 1024 + j];
    }
#pragma unroll
    for (int r = 0; r < 4; r++) {
      const int m = m0 + quad * 4 + r;
      float gate[4];
#pragma unroll
      for (int g = 0; g < 4; g++) {
        gate[g] = ig[g][r] * (pg0[g][r] + pb0[g])
                + hg[g][r] * (pg1[g][r] + pb1[g])
                + fbv[g]   * (redP[mw][g][lane][r] + pb2[g]);
      }
      const float i_ = sigm(gate[0]);
      const float f_ = sigm(gate[1]);
      const float g_ = tanh_f(gate[2]);
      const float o_ = sigm(gate[3]);
      const int idx = m * 1024 + j;
      const float c2 = f_ * cbuf[idx] + i_ * g_;   // c-state: block-private, cached
      cbuf[idx] = c2;
      const float h = o_ * tanh_f(c2);
      stc_bf(&hbuf[idx], f2bf(h));                 // h: cross-block -> coherent
      if (outp) __builtin_nontemporal_store(h, &outp[idx]);  // keep L2 clean
    }
  }
}

// ---------- the persistent kernel: all 512 steps, 4 barrier slots per step ----------
// Steady-state schedule (cycle t): A:{S3(t)} B:{S4(t)} C:{S5(t) || S1(t+1)} D:{S6(t) || S2(t+1)}
__global__ __launch_bounds__(256) void alstm_persistent(
    const unsigned short* __restrict__ xb, float* __restrict__ out,
    const unsigned short* __restrict__ a_wih0b, const unsigned short* __restrict__ a_whh0b,
    const float* __restrict__ a_bih0, const float* __restrict__ a_bhh0,
    const unsigned short* __restrict__ p_w0b, const float* __restrict__ p_b0,
    const unsigned short* __restrict__ f_wih0b, const unsigned short* __restrict__ f_whh0b,
    const float* __restrict__ f_b0,
    const unsigned short* __restrict__ a_wih1b, const unsigned short* __restrict__ a_whh1b,
    const float* __restrict__ a_bih1, const float* __restrict__ a_bhh1,
    const unsigned short* __restrict__ p_w1b, const float* __restrict__ p_b1,
    const unsigned short* __restrict__ f_wih1b, const unsigned short* __restrict__ f_whh1b,
    const float* __restrict__ f_b1,
    float* a0c, float* a1c, float* f0c, float* f1c,
    unsigned short* a0xA, unsigned short* a0xB,
    unsigned short* a1xA, unsigned short* a1xB,
    unsigned short* f0x, unsigned short* f1x,
    unsigned short* xh0, unsigned short* hh0,
    unsigned short* xh1, unsigned short* hh1,
    unsigned* bar)
{
  const int blk = blockIdx.x;
  unsigned ep = 0;

  // prologue: S1(0) then S2(0)
  if (blk >= 32 && blk < 64)
    st_adapt<8, 32, 4, 4>(blk - 32,
        xb, 256, a_wih0b, 1408,
        f0x, 1024, a_wih0b + 256, 1408,
        a1xB, 128, a_wih0b + 1280, 1408,
        a0xB, 128, a_whh0b, 128,
        a_bih0, a_bhh0, a0c, a0xA);
  gbar(bar, ++ep * (unsigned)G_BLOCKS);
  if (blk >= 128 && blk < 148)
    st_policy(blk - 128, a0xA, p_w0b, p_b0, xb, 256, f0x, 1024, xh0, hh0);
  gbar(bar, ++ep * (unsigned)G_BLOCKS);

#pragma unroll 1
  for (int t = 0; t < 512; t++) {
    const unsigned short* xt1 = xb + (size_t)(t + 1) * 64 * 256;
    unsigned short* a0x_cur  = (t & 1) ? a0xB : a0xA;
    unsigned short* a0x_nxt  = (t & 1) ? a0xA : a0xB;
    unsigned short* a1x_cur  = (t & 1) ? a1xB : a1xA;
    unsigned short* a1x_prev = (t & 1) ? a1xA : a1xB;
    const bool more = (t + 1 < 512);

    // slot A: S3(t) = f-cell 0
    if (blk < 128)
      st_fcell<256, 1024>(blk, xh0, hh0, f_wih0b, f_whh0b, f_b0,
                          a0x_cur, p_w0b, p_b0, 1280, 5376, 9472,
                          f0c, f0x, (float*)nullptr);
    gbar(bar, ++ep * (unsigned)G_BLOCKS);

    // slot B: S4(t) = adapt cell 1
    if (blk < 32)
      st_adapt<32, 32, 4, 4>(blk,
          f0x, 1024, a_wih1b, 2176,
          f1x, 1024, a_wih1b + 1024, 2176,
          a0x_cur, 128, a_wih1b + 2048, 2176,
          a1x_prev, 128, a_whh1b, 128,
          a_bih1, a_bhh1, a1c, a1x_cur);
    gbar(bar, ++ep * (unsigned)G_BLOCKS);

    // slot C: S5(t) = policy 1  ||  S1(t+1) = adapt cell 0
    if (blk < 32)
      st_policy(blk, a1x_cur, p_w1b, p_b1, f0x, 1024, f1x, 1024, xh1, hh1);
    else if (blk < 64 && more)
      st_adapt<8, 32, 4, 4>(blk - 32,
          xt1, 256, a_wih0b, 1408,
          f0x, 1024, a_wih0b + 256, 1408,
          a1x_cur, 128, a_wih0b + 1280, 1408,
          a0x_cur, 128, a_whh0b, 128,
          a_bih0, a_bhh0, a0c, a0x_nxt);
    gbar(bar, ++ep * (unsigned)G_BLOCKS);

    // slot D: S6(t) = f-cell 1  ||  S2(t+1) = policy 0
    if (blk < 128)
      st_fcell<1024, 1024>(blk, xh1, hh1, f_wih1b, f_whh1b, f_b1,
                           a1x_cur, p_w1b, p_b1, 2048, 6144, 10240,
                           f1c, f1x, out + (size_t)t * 64 * 1024);
    else if (blk < 148 && more)
      st_policy(blk - 128, a0x_nxt, p_w0b, p_b0, xt1, 256, f0x, 1024, xh0, hh0);
    gbar(bar, ++ep * (unsigned)G_BLOCKS);
  }
}

extern "C" void kernel_launch(void* const* d_in, const int* in_sizes, int n_in,
                              void* d_out, int out_size, void* d_ws, size_t ws_size,
                              hipStream_t stream)
{
  const float* x      = (const float*)d_in[0];
  const float* a_wih0 = (const float*)d_in[1];
  const float* a_whh0 = (const float*)d_in[2];
  const float* a_bih0 = (const float*)d_in[3];
  const float* a_bhh0 = (const float*)d_in[4];
  const float* p_w0   = (const float*)d_in[5];
  const float* p_b0   = (const float*)d_in[6];
  const float* f_wih0 = (const float*)d_in[7];
  const float* f_whh0 = (const float*)d_in[8];
  const float* f_b0   = (const float*)d_in[9];
  const float* a_wih1 = (const float*)d_in[10];
  const float* a_whh1 = (const float*)d_in[11];
  const float* a_bih1 = (const float*)d_in[12];
  const float* a_bhh1 = (const float*)d_in[13];
  const float* p_w1   = (const float*)d_in[14];
  const float* p_b1   = (const float*)d_in[15];
  const float* f_wih1 = (const float*)d_in[16];
  const float* f_whh1 = (const float*)d_in[17];
  const float* f_b1   = (const float*)d_in[18];
  float* out = (float*)d_out;

  // ---- workspace carve-up (256B-aligned cursor) ----
  char* p = (char*)d_ws;
  auto alloc = [&](size_t bytes) { char* r = p; p += (bytes + 255) & ~(size_t)255; return r; };

  // zeroed each launch: barrier counter + recurrent state
  unsigned* bar = (unsigned*)alloc(256);
  float* a0c = (float*)alloc(64 * 128 * 4);
  float* a1c = (float*)alloc(64 * 128 * 4);
  float* f0c = (float*)alloc(64 * 1024 * 4);
  float* f1c = (float*)alloc(64 * 1024 * 4);
  unsigned short* a0xA = (unsigned short*)alloc(64 * 128 * 2);
  unsigned short* a0xB = (unsigned short*)alloc(64 * 128 * 2);
  unsigned short* a1xA = (unsigned short*)alloc(64 * 128 * 2);
  unsigned short* a1xB = (unsigned short*)alloc(64 * 128 * 2);
  unsigned short* f0x  = (unsigned short*)alloc(64 * 1024 * 2);
  unsigned short* f1x  = (unsigned short*)alloc(64 * 1024 * 2);
  const size_t zero_bytes = (size_t)(p - (char*)d_ws);

  // per-step scratch (fully written before read each step)
  unsigned short* xh0 = (unsigned short*)alloc(64 * 256 * 2);
  unsigned short* hh0 = (unsigned short*)alloc(64 * 1024 * 2);
  unsigned short* xh1 = (unsigned short*)alloc(64 * 1024 * 2);
  unsigned short* hh1 = (unsigned short*)alloc(64 * 1024 * 2);

  // bf16 conversions of x + weights
  unsigned short* xb      = (unsigned short*)alloc((size_t)8388608 * 2);
  unsigned short* a_wih0b = (unsigned short*)alloc((size_t)720896 * 2);
  unsigned short* a_whh0b = (unsigned short*)alloc((size_t)65536 * 2);
  unsigned short* p_w0b   = (unsigned short*)alloc((size_t)1736704 * 2);
  unsigned short* f_wih0b = (unsigned short*)alloc((size_t)1048576 * 2);
  unsigned short* f_whh0b = (unsigned short*)alloc((size_t)4194304 * 2);
  unsigned short* a_wih1b = (unsigned short*)alloc((size_t)1114112 * 2);
  unsigned short* a_whh1b = (unsigned short*)alloc((size_t)65536 * 2);
  unsigned short* p_w1b   = (unsigned short*)alloc((size_t)1835008 * 2);
  unsigned short* f_wih1b = (unsigned short*)alloc((size_t)4194304 * 2);
  unsigned short* f_whh1b = (unsigned short*)alloc((size_t)4194304 * 2);

  hipMemsetAsync(d_ws, 0, zero_bytes, stream);

  auto conv = [&](const float* s, unsigned short* d, size_t n) {
    int n4 = (int)(n >> 2);
    int blocks = (n4 + 255) / 256; if (blocks > 1024) blocks = 1024;
    f32_to_bf16<<<blocks, 256, 0, stream>>>(s, d, n4);
  };
  conv(x,      xb,      8388608);
  conv(a_wih0, a_wih0b, 720896);
  conv(a_whh0, a_whh0b, 65536);
  conv(p_w0,   p_w0b,   1736704);
  conv(f_wih0, f_wih0b, 1048576);
  conv(f_whh0, f_whh0b, 4194304);
  conv(a_wih1, a_wih1b, 1114112);
  conv(a_whh1, a_whh1b, 65536);
  conv(p_w1,   p_w1b,   1835008);
  conv(f_wih1, f_wih1b, 4194304);
  conv(f_whh1, f_whh1b, 4194304);

  alstm_persistent<<<G_BLOCKS, 256, 0, stream>>>(
      xb, out,
      a_wih0b, a_whh0b, a_bih0, a_bhh0, p_w0b, p_b0, f_wih0b, f_whh0b, f_b0,
      a_wih1b, a_whh1b, a_bih1, a_bhh1, p_w1b, p_b1, f_wih1b, f_whh1b, f_b1,
      a0c, a1c, f0c, f1c, a0xA, a0xB, a1xA, a1xB, f0x, f1x,
      xh0, hh0, xh1, hh1, bar);
}

// Round 4
// 69122.937 us; speedup vs baseline: 1.3528x; 1.0765x over previous
//
#include <hip/hip_runtime.h>

// ---------- types & helpers ----------
typedef __bf16 bf16x8 __attribute__((ext_vector_type(8)));
typedef float  f32x4  __attribute__((ext_vector_type(4)));

#define AS __HIP_MEMORY_SCOPE_AGENT

__device__ __forceinline__ float bf2f(unsigned short u) {
  union { unsigned int i; float f; } v; v.i = ((unsigned int)u) << 16; return v.f;
}
__device__ __forceinline__ unsigned short f2bf(float f) {
  union { float f; unsigned int u; } v; v.f = f;
  unsigned int r = v.u + 0x7fffu + ((v.u >> 16) & 1u);
  return (unsigned short)(r >> 16);
}
__device__ __forceinline__ float sigm(float x)   { return 1.f / (1.f + __expf(-x)); }
__device__ __forceinline__ float tanh_f(float x) { return 2.f / (1.f + __expf(-2.f * x)) - 1.f; }

// cached load (weights / immutable data only)
__device__ __forceinline__ bf16x8 ld8(const unsigned short* p) {
  return *reinterpret_cast<const bf16x8*>(p);
}
// coherent (agent-scope) accessors for cross-block mutable buffers: sc0/sc1, always fresh.
__device__ __forceinline__ bf16x8 ldc8(const unsigned short* p) {
  const unsigned long long* q = (const unsigned long long*)p;
  union { unsigned long long u[2]; bf16x8 v; } r;
  r.u[0] = __hip_atomic_load(q + 0, __ATOMIC_RELAXED, AS);
  r.u[1] = __hip_atomic_load(q + 1, __ATOMIC_RELAXED, AS);
  return r.v;
}
__device__ __forceinline__ unsigned short ldc_bf(const unsigned short* p) {
  return __hip_atomic_load(p, __ATOMIC_RELAXED, AS);
}
__device__ __forceinline__ void stc_bf(unsigned short* p, unsigned short v) {
  __hip_atomic_store(p, v, __ATOMIC_RELAXED, AS);
}
__device__ __forceinline__ void stc2f(float* p, float a, float b) {
  union { float f[2]; unsigned long long u; } v; v.f[0] = a; v.f[1] = b;
  __hip_atomic_store((unsigned long long*)p, v.u, __ATOMIC_RELAXED, AS);
}
__device__ __forceinline__ void ldc2f(const float* p, float& a, float& b) {
  union { unsigned long long u; float f[2]; } v;
  v.u = __hip_atomic_load((const unsigned long long*)p, __ATOMIC_RELAXED, AS);
  a = v.f[0]; b = v.f[1];
}

// ---------- fp32 -> bf16 bulk convert (weights & x), once per launch ----------
__global__ __launch_bounds__(256) void f32_to_bf16(const float* __restrict__ src,
                                                   unsigned short* __restrict__ dst, int n4) {
  int i = blockIdx.x * blockDim.x + threadIdx.x;
  const int stride = gridDim.x * blockDim.x;
  const float4* s4 = (const float4*)src;
  ushort4* d4 = (ushort4*)dst;
  for (; i < n4; i += stride) {
    float4 v = s4[i];
    ushort4 o;
    o.x = f2bf(v.x); o.y = f2bf(v.y); o.z = f2bf(v.z); o.w = f2bf(v.w);
    d4[i] = o;
  }
}

// ---------- LDS layout: f-cell weights resident for all 512 steps ----------
struct SMem {
  unsigned short w1[16 * 64 * 32];  // layer1 quarter: 16 chunks x 64 rows x 32  (64KB)
  unsigned short w0[10 * 64 * 32];  // layer0 quarter: 10 chunks x 64 rows x 32  (40KB)
  f32x4 red_a[3][4][64];            // adapt-cell K-reduction scratch (12KB)
};

// ---------- grid barrier: NO cache invalidation (agent-scope data flow) ----------
#define G_BLOCKS 256
__device__ __forceinline__ void gbar(unsigned* bar, unsigned target) {
  asm volatile("s_waitcnt vmcnt(0)" ::: "memory");
  __syncthreads();
  if (threadIdx.x == 0) {
    __hip_atomic_fetch_add(bar, 1u, __ATOMIC_RELAXED, AS);
    while (__hip_atomic_load(bar, __ATOMIC_RELAXED, AS) < target) {
      __builtin_amdgcn_s_sleep(2);
    }
  }
  __syncthreads();
  asm volatile("" ::: "memory");
}

// ---------- preload this block's f-cell weight K-quarter into LDS ----------
template<int XK, int HK>
__device__ __forceinline__ void preload(unsigned short* wl,
    const unsigned short* __restrict__ wih, const unsigned short* __restrict__ whh,
    int kq, int jb)
{
  constexpr int XC = XK / 32, CT = (XK + HK) / 32, CQ = CT / 4;
  const int c0 = kq * CQ, j0 = jb * 16;
  for (int it = threadIdx.x; it < CQ * 64; it += 256) {
    const int lc = it >> 6, r = it & 63;          // r = g*16 + jj
    const int g = r >> 4, jj = r & 15;
    const int cg = c0 + lc;
    const unsigned short* src = (cg < XC)
        ? wih + (size_t)(g * 1024 + j0 + jj) * XK + cg * 32
        : whh + (size_t)(g * 1024 + j0 + jj) * HK + (cg - XC) * 32;
    ulonglong2* d = (ulonglong2*)(wl + (size_t)it * 32);
    const ulonglong2* s = (const ulonglong2*)src;
    d[0] = s[0]; d[1] = s[1]; d[2] = s[2]; d[3] = s[3];
  }
}

// ---------- stage: standard LSTM cell (adapt). 32 blocks x 4 waves (K-quarters) ----------
// rel -> j0=(rel&7)*16, m0=(rel>>3)*16 : m-duplicate group {j, j+8, j+16, j+24} shares XCD.
template<int C>
__device__ __forceinline__ void seg_quarter(f32x4 acc[4],
    const unsigned short* __restrict__ a, int astride,
    const unsigned short* __restrict__ w, int wstride,
    int m0, int j0, int quad, int col, int kq)
{
  constexpr int CQ = C / 4;
  const unsigned short* ar = a + (size_t)(m0 + col) * astride + quad * 8 + kq * CQ * 32;
  const unsigned short* wr = w + quad * 8 + kq * CQ * 32;
#pragma unroll
  for (int c = 0; c < CQ; c++) {
    bf16x8 af = ldc8(ar + c * 32);
#pragma unroll
    for (int g = 0; g < 4; g++) {
      acc[g] = __builtin_amdgcn_mfma_f32_16x16x32_bf16(
          af, ld8(wr + (size_t)(g * 128 + j0 + col) * wstride + c * 32),
          acc[g], 0, 0, 0);
    }
  }
}

template<int C0, int C1, int C2, int C3>
__device__ __forceinline__ void st_adapt(SMem& sm, int rel,
    const unsigned short* __restrict__ a0, int as0, const unsigned short* __restrict__ w0, int ws0,
    const unsigned short* __restrict__ a1, int as1, const unsigned short* __restrict__ w1, int ws1,
    const unsigned short* __restrict__ a2, int as2, const unsigned short* __restrict__ w2, int ws2,
    const unsigned short* __restrict__ a3, int as3, const unsigned short* __restrict__ w3, int ws3,
    const float* __restrict__ bih, const float* __restrict__ bhh,
    float* __restrict__ cbuf, unsigned short* __restrict__ hbuf)
{
  const int tid = threadIdx.x;
  const int kq = tid >> 6, lane = tid & 63;
  const int quad = lane >> 4, col = lane & 15;
  const int j0 = (rel & 7) * 16, m0 = (rel >> 3) * 16;

  f32x4 acc[4] = {};
  seg_quarter<C0>(acc, a0, as0, w0, ws0, m0, j0, quad, col, kq);
  seg_quarter<C1>(acc, a1, as1, w1, ws1, m0, j0, quad, col, kq);
  seg_quarter<C2>(acc, a2, as2, w2, ws2, m0, j0, quad, col, kq);
  seg_quarter<C3>(acc, a3, as3, w3, ws3, m0, j0, quad, col, kq);

  if (kq) {
#pragma unroll
    for (int g = 0; g < 4; g++) sm.red_a[kq - 1][g][lane] = acc[g];
  }
  __syncthreads();
  if (kq == 0) {
#pragma unroll
    for (int p = 0; p < 3; p++)
#pragma unroll
      for (int g = 0; g < 4; g++) acc[g] += sm.red_a[p][g][lane];

    const int j = j0 + col;
    const float b0 = bih[j]       + bhh[j];
    const float b1 = bih[128 + j] + bhh[128 + j];
    const float b2 = bih[256 + j] + bhh[256 + j];
    const float b3 = bih[384 + j] + bhh[384 + j];
#pragma unroll
    for (int r = 0; r < 4; r++) {
      const int m = m0 + quad * 4 + r;
      const float i_ = sigm(acc[0][r] + b0);
      const float f_ = sigm(acc[1][r] + b1);
      const float g_ = tanh_f(acc[2][r] + b2);
      const float o_ = sigm(acc[3][r] + b3);
      const int idx = m * 128 + j;
      const float c2 = f_ * cbuf[idx] + i_ * g_;   // block-private, cached
      cbuf[idx] = c2;
      stc_bf(&hbuf[idx], f2bf(o_ * tanh_f(c2)));   // cross-block -> coherent
    }
  }
  __syncthreads();  // protect red_a reuse
}

// ---------- stage: x-hat / h-hat production. N/64 blocks x 4 waves ----------
__device__ __forceinline__ void st_policy(int blk,
    const unsigned short* __restrict__ A,
    const unsigned short* __restrict__ pw, const float* __restrict__ pb,
    const unsigned short* __restrict__ xsrc, int xn,
    const unsigned short* __restrict__ hsrc, int hn,
    unsigned short* __restrict__ xhat, unsigned short* __restrict__ hhat)
{
  const int wave = threadIdx.x >> 6, lane = threadIdx.x & 63;
  const int quad = lane >> 4, col = lane & 15;
  const int m0 = wave * 16, n0 = blk * 64;

  f32x4 acc[4] = {};
  const unsigned short* arow = A + (size_t)(m0 + col) * 128 + quad * 8;
#pragma unroll
  for (int c = 0; c < 4; c++) {
    bf16x8 af = ldc8(arow + c * 32);
#pragma unroll
    for (int s = 0; s < 4; s++) {
      acc[s] = __builtin_amdgcn_mfma_f32_16x16x32_bf16(
          af, ld8(pw + (size_t)(n0 + s * 16 + col) * 128 + quad * 8 + c * 32),
          acc[s], 0, 0, 0);
    }
  }
#pragma unroll
  for (int s = 0; s < 4; s++) {
    const int n = n0 + s * 16 + col;
    const float bias = pb[n];
#pragma unroll
    for (int r = 0; r < 4; r++) {
      const int m = m0 + quad * 4 + r;
      const float v = acc[s][r] + bias;
      if (n < xn) {
        stc_bf(&xhat[m * xn + n], f2bf(v * bf2f(ldc_bf(&xsrc[m * xn + n]))));
      } else {
        stc_bf(&hhat[m * hn + (n - xn)], f2bf(v * bf2f(ldc_bf(&hsrc[m * hn + (n - xn)]))));
      }
    }
  }
}

// ---------- stage: adaptive LSTM f-cell. ALL 256 blocks = 64 j x 4 K-quarters ----------
// Weights read from LDS (resident). kq=1..3: GEMM quarter -> agent partials -> flag.
// kq=0: policy slices + GEMM quarter + wait + deterministic combine + epilogue.
template<int XK, int HK>
__device__ __forceinline__ void st_fcell(SMem& sm, int jb, int kq,
    const unsigned short* __restrict__ xhat, const unsigned short* __restrict__ hhat,
    const float* __restrict__ fb, const unsigned short* __restrict__ ax,
    const unsigned short* __restrict__ pw, const float* __restrict__ pb,
    int ig_off, int hg_off, int ab_off,
    float* __restrict__ cbuf, unsigned short* __restrict__ hbuf, float* __restrict__ outp,
    float* __restrict__ pbuf, unsigned* fcnt, unsigned ftarget)
{
  constexpr int XC = XK / 32, CT = (XK + HK) / 32, CQ = CT / 4;
  const int tid = threadIdx.x;
  const int wave = tid >> 6, lane = tid & 63;
  const int quad = lane >> 4, col = lane & 15;
  const int m0 = wave * 16, j0 = jb * 16, c0 = kq * CQ;
  const unsigned short* wl = (XK == 1024) ? sm.w1 : sm.w0;

  // kq0: policy gate-scale slices first (pw L2-resident, ax agent)
  f32x4 pg0[4] = {}, pg1[4] = {}, pg2[4] = {};
  if (kq == 0) {
    const unsigned short* ar = ax + (size_t)(m0 + col) * 128 + quad * 8;
#pragma unroll
    for (int c = 0; c < 4; c++) {
      bf16x8 af = ldc8(ar + c * 32);
#pragma unroll
      for (int g = 0; g < 4; g++) {
        pg0[g] = __builtin_amdgcn_mfma_f32_16x16x32_bf16(
            af, ld8(pw + (size_t)(ig_off + g * 1024 + j0 + col) * 128 + quad * 8 + c * 32), pg0[g], 0, 0, 0);
        pg1[g] = __builtin_amdgcn_mfma_f32_16x16x32_bf16(
            af, ld8(pw + (size_t)(hg_off + g * 1024 + j0 + col) * 128 + quad * 8 + c * 32), pg1[g], 0, 0, 0);
        pg2[g] = __builtin_amdgcn_mfma_f32_16x16x32_bf16(
            af, ld8(pw + (size_t)(ab_off + g * 1024 + j0 + col) * 128 + quad * 8 + c * 32), pg2[g], 0, 0, 0);
      }
    }
  }

  // GEMM quarter from LDS weights; ig (x-part) and hg (h-part) kept separate
  f32x4 ai[4] = {}, ah[4] = {};
#pragma unroll
  for (int lc = 0; lc < CQ; lc++) {
    const int cg = c0 + lc;
    const unsigned short* wr = wl + lc * 2048 + quad * 8;  // 64 rows x 32 per chunk
    if (cg < XC) {
      bf16x8 af = ldc8(xhat + (size_t)(m0 + col) * XK + cg * 32 + quad * 8);
#pragma unroll
      for (int g = 0; g < 4; g++)
        ai[g] = __builtin_amdgcn_mfma_f32_16x16x32_bf16(af, ld8(wr + (g * 16 + col) * 32), ai[g], 0, 0, 0);
    } else {
      bf16x8 af = ldc8(hhat + (size_t)(m0 + col) * HK + (cg - XC) * 32 + quad * 8);
#pragma unroll
      for (int g = 0; g < 4; g++)
        ah[g] = __builtin_amdgcn_mfma_f32_16x16x32_bf16(af, ld8(wr + (g * 16 + col) * 32), ah[g], 0, 0, 0);
    }
  }

  if (kq) {
    // publish partials (agent), then arrive
#pragma unroll
    for (int g = 0; g < 4; g++) {
      float* pi = pbuf + ((((((kq - 1) * 64 + jb) * 2 + 0) * 4 + wave) * 4 + g) * 64 + lane) * 4;
      float* ph = pbuf + ((((((kq - 1) * 64 + jb) * 2 + 1) * 4 + wave) * 4 + g) * 64 + lane) * 4;
      stc2f(pi, ai[g][0], ai[g][1]); stc2f(pi + 2, ai[g][2], ai[g][3]);
      stc2f(ph, ah[g][0], ah[g][1]); stc2f(ph + 2, ah[g][2], ah[g][3]);
    }
    asm volatile("s_waitcnt vmcnt(0)" ::: "memory");
    __syncthreads();
    if (tid == 0) __hip_atomic_fetch_add(&fcnt[jb], 1u, __ATOMIC_RELAXED, AS);
    return;
  }

  // kq0: wait for 3 siblings, combine in fixed order (deterministic)
  if (tid == 0) {
    while (__hip_atomic_load(&fcnt[jb], __ATOMIC_RELAXED, AS) < ftarget)
      __builtin_amdgcn_s_sleep(1);
  }
  __syncthreads();
  asm volatile("" ::: "memory");
#pragma unroll
  for (int kk = 0; kk < 3; kk++) {
#pragma unroll
    for (int g = 0; g < 4; g++) {
      const float* pi = pbuf + (((((kk * 64 + jb) * 2 + 0) * 4 + wave) * 4 + g) * 64 + lane) * 4;
      const float* ph = pbuf + (((((kk * 64 + jb) * 2 + 1) * 4 + wave) * 4 + g) * 64 + lane) * 4;
      float a, b, c, d;
      ldc2f(pi, a, b); ldc2f(pi + 2, c, d);
      ai[g][0] += a; ai[g][1] += b; ai[g][2] += c; ai[g][3] += d;
      ldc2f(ph, a, b); ldc2f(ph + 2, c, d);
      ah[g][0] += a; ah[g][1] += b; ah[g][2] += c; ah[g][3] += d;
    }
  }

  const int j = j0 + col;
  float pbi[4], pbh[4], pba[4], fbv[4];
#pragma unroll
  for (int g = 0; g < 4; g++) {
    pbi[g] = pb[ig_off + g * 1024 + j];
    pbh[g] = pb[hg_off + g * 1024 + j];
    pba[g] = pb[ab_off + g * 1024 + j];
    fbv[g] = fb[g * 1024 + j];
  }
#pragma unroll
  for (int r = 0; r < 4; r++) {
    const int m = m0 + quad * 4 + r;
    float gate[4];
#pragma unroll
    for (int g = 0; g < 4; g++) {
      gate[g] = ai[g][r] * (pg0[g][r] + pbi[g])
              + ah[g][r] * (pg1[g][r] + pbh[g])
              + fbv[g]   * (pg2[g][r] + pba[g]);
    }
    const float i_ = sigm(gate[0]);
    const float f_ = sigm(gate[1]);
    const float g_ = tanh_f(gate[2]);
    const float o_ = sigm(gate[3]);
    const int idx = m * 1024 + j;
    const float c2 = f_ * cbuf[idx] + i_ * g_;   // block-private, cached
    cbuf[idx] = c2;
    const float h = o_ * tanh_f(c2);
    stc_bf(&hbuf[idx], f2bf(h));                 // cross-block -> coherent
    if (outp) __builtin_nontemporal_store(h, &outp[idx]);
  }
}

// ---------- the persistent kernel: 4 barrier slots per step ----------
// A:{fcell0 (256 blk)} B:{adapt1 (32)} C:{policy1 (32) || adapt0(t+1) (32)}
// D:{fcell1 (256) ; policy0(t+1) on kq3/jb<20 after sibling duty}
__global__ __launch_bounds__(256) void alstm_persistent(
    const unsigned short* __restrict__ xb, float* __restrict__ out,
    const unsigned short* __restrict__ a_wih0b, const unsigned short* __restrict__ a_whh0b,
    const float* __restrict__ a_bih0, const float* __restrict__ a_bhh0,
    const unsigned short* __restrict__ p_w0b, const float* __restrict__ p_b0,
    const unsigned short* __restrict__ f_wih0b, const unsigned short* __restrict__ f_whh0b,
    const float* __restrict__ f_b0,
    const unsigned short* __restrict__ a_wih1b, const unsigned short* __restrict__ a_whh1b,
    const float* __restrict__ a_bih1, const float* __restrict__ a_bhh1,
    const unsigned short* __restrict__ p_w1b, const float* __restrict__ p_b1,
    const unsigned short* __restrict__ f_wih1b, const unsigned short* __restrict__ f_whh1b,
    const float* __restrict__ f_b1,
    float* a0c, float* a1c, float* f0c, float* f1c,
    unsigned short* a0xA, unsigned short* a0xB,
    unsigned short* a1xA, unsigned short* a1xB,
    unsigned short* f0x, unsigned short* f1x,
    unsigned short* xh0, unsigned short* hh0,
    unsigned short* xh1, unsigned short* hh1,
    float* pbuf, unsigned* fcnt, unsigned* bar)
{
  __shared__ SMem sm;
  const int blk = blockIdx.x;
  const int jb = blk & 63, kq = blk >> 6;
  unsigned ep = 0, fc_ep = 0;

  // one-time: stage this block's f-cell weight quarters into LDS
  preload<1024, 1024>(sm.w1, f_wih1b, f_whh1b, kq, jb);
  preload<256,  1024>(sm.w0, f_wih0b, f_whh0b, kq, jb);
  __syncthreads();

  // prologue: S1(0) then S2(0)
  if (blk >= 32 && blk < 64)
    st_adapt<8, 32, 4, 4>(sm, blk - 32,
        xb, 256, a_wih0b, 1408,
        f0x, 1024, a_wih0b + 256, 1408,
        a1xB, 128, a_wih0b + 1280, 1408,
        a0xB, 128, a_whh0b, 128,
        a_bih0, a_bhh0, a0c, a0xA);
  gbar(bar, ++ep * (unsigned)G_BLOCKS);
  if (kq == 3 && jb < 20)
    st_policy(jb, a0xA, p_w0b, p_b0, xb, 256, f0x, 1024, xh0, hh0);
  gbar(bar, ++ep * (unsigned)G_BLOCKS);

#pragma unroll 1
  for (int t = 0; t < 512; t++) {
    const unsigned short* xt1 = xb + (size_t)(t + 1) * 64 * 256;
    unsigned short* a0x_cur  = (t & 1) ? a0xB : a0xA;
    unsigned short* a0x_nxt  = (t & 1) ? a0xA : a0xB;
    unsigned short* a1x_cur  = (t & 1) ? a1xB : a1xA;
    unsigned short* a1x_prev = (t & 1) ? a1xA : a1xB;
    const bool more = (t + 1 < 512);

    // slot A: f-cell 0 (all blocks)
    fc_ep++;
    st_fcell<256, 1024>(sm, jb, kq, xh0, hh0, f_b0,
                        a0x_cur, p_w0b, p_b0, 1280, 5376, 9472,
                        f0c, f0x, (float*)nullptr, pbuf, fcnt, 3u * fc_ep);
    gbar(bar, ++ep * (unsigned)G_BLOCKS);

    // slot B: adapt cell 1
    if (blk < 32)
      st_adapt<32, 32, 4, 4>(sm, blk,
          f0x, 1024, a_wih1b, 2176,
          f1x, 1024, a_wih1b + 1024, 2176,
          a0x_cur, 128, a_wih1b + 2048, 2176,
          a1x_prev, 128, a_whh1b, 128,
          a_bih1, a_bhh1, a1c, a1x_cur);
    gbar(bar, ++ep * (unsigned)G_BLOCKS);

    // slot C: policy 1 || adapt cell 0 (t+1)
    if (blk < 32)
      st_policy(blk, a1x_cur, p_w1b, p_b1, f0x, 1024, f1x, 1024, xh1, hh1);
    else if (blk < 64 && more)
      st_adapt<8, 32, 4, 4>(sm, blk - 32,
          xt1, 256, a_wih0b, 1408,
          f0x, 1024, a_wih0b + 256, 1408,
          a1x_cur, 128, a_wih0b + 1280, 1408,
          a0x_cur, 128, a_whh0b, 128,
          a_bih0, a_bhh0, a0c, a0x_nxt);
    gbar(bar, ++ep * (unsigned)G_BLOCKS);

    // slot D: f-cell 1 (all blocks); kq3/jb<20 siblings then run policy 0 (t+1)
    fc_ep++;
    st_fcell<1024, 1024>(sm, jb, kq, xh1, hh1, f_b1,
                         a1x_cur, p_w1b, p_b1, 2048, 6144, 10240,
                         f1c, f1x, out + (size_t)t * 64 * 1024, pbuf, fcnt, 3u * fc_ep);
    if (kq == 3 && jb < 20 && more)
      st_policy(jb, a0x_nxt, p_w0b, p_b0, xt1, 256, f0x, 1024, xh0, hh0);
    gbar(bar, ++ep * (unsigned)G_BLOCKS);
  }
}

extern "C" void kernel_launch(void* const* d_in, const int* in_sizes, int n_in,
                              void* d_out, int out_size, void* d_ws, size_t ws_size,
                              hipStream_t stream)
{
  const float* x      = (const float*)d_in[0];
  const float* a_wih0 = (const float*)d_in[1];
  const float* a_whh0 = (const float*)d_in[2];
  const float* a_bih0 = (const float*)d_in[3];
  const float* a_bhh0 = (const float*)d_in[4];
  const float* p_w0   = (const float*)d_in[5];
  const float* p_b0   = (const float*)d_in[6];
  const float* f_wih0 = (const float*)d_in[7];
  const float* f_whh0 = (const float*)d_in[8];
  const float* f_b0   = (const float*)d_in[9];
  const float* a_wih1 = (const float*)d_in[10];
  const float* a_whh1 = (const float*)d_in[11];
  const float* a_bih1 = (const float*)d_in[12];
  const float* a_bhh1 = (const float*)d_in[13];
  const float* p_w1   = (const float*)d_in[14];
  const float* p_b1   = (const float*)d_in[15];
  const float* f_wih1 = (const float*)d_in[16];
  const float* f_whh1 = (const float*)d_in[17];
  const float* f_b1   = (const float*)d_in[18];
  float* out = (float*)d_out;

  // ---- workspace carve-up (256B-aligned cursor) ----
  char* p = (char*)d_ws;
  auto alloc = [&](size_t bytes) { char* r = p; p += (bytes + 255) & ~(size_t)255; return r; };

  // zeroed each launch: barrier + fcell flags + recurrent state
  unsigned* bar  = (unsigned*)alloc(256);
  unsigned* fcnt = (unsigned*)alloc(256);
  float* a0c = (float*)alloc(64 * 128 * 4);
  float* a1c = (float*)alloc(64 * 128 * 4);
  float* f0c = (float*)alloc(64 * 1024 * 4);
  float* f1c = (float*)alloc(64 * 1024 * 4);
  unsigned short* a0xA = (unsigned short*)alloc(64 * 128 * 2);
  unsigned short* a0xB = (unsigned short*)alloc(64 * 128 * 2);
  unsigned short* a1xA = (unsigned short*)alloc(64 * 128 * 2);
  unsigned short* a1xB = (unsigned short*)alloc(64 * 128 * 2);
  unsigned short* f0x  = (unsigned short*)alloc(64 * 1024 * 2);
  unsigned short* f1x  = (unsigned short*)alloc(64 * 1024 * 2);
  const size_t zero_bytes = (size_t)(p - (char*)d_ws);

  // per-step scratch (fully written before read each step)
  unsigned short* xh0 = (unsigned short*)alloc(64 * 256 * 2);
  unsigned short* hh0 = (unsigned short*)alloc(64 * 1024 * 2);
  unsigned short* xh1 = (unsigned short*)alloc(64 * 1024 * 2);
  unsigned short* hh1 = (unsigned short*)alloc(64 * 1024 * 2);
  float* pbuf = (float*)alloc((size_t)3 * 64 * 2 * 16 * 64 * 4 * 4);  // 6MB partials

  // bf16 conversions of x + weights
  unsigned short* xb      = (unsigned short*)alloc((size_t)8388608 * 2);
  unsigned short* a_wih0b = (unsigned short*)alloc((size_t)720896 * 2);
  unsigned short* a_whh0b = (unsigned short*)alloc((size_t)65536 * 2);
  unsigned short* p_w0b   = (unsigned short*)alloc((size_t)1736704 * 2);
  unsigned short* f_wih0b = (unsigned short*)alloc((size_t)1048576 * 2);
  unsigned short* f_whh0b = (unsigned short*)alloc((size_t)4194304 * 2);
  unsigned short* a_wih1b = (unsigned short*)alloc((size_t)1114112 * 2);
  unsigned short* a_whh1b = (unsigned short*)alloc((size_t)65536 * 2);
  unsigned short* p_w1b   = (unsigned short*)alloc((size_t)1835008 * 2);
  unsigned short* f_wih1b = (unsigned short*)alloc((size_t)4194304 * 2);
  unsigned short* f_whh1b = (unsigned short*)alloc((size_t)4194304 * 2);

  hipMemsetAsync(d_ws, 0, zero_bytes, stream);

  auto conv = [&](const float* s, unsigned short* d, size_t n) {
    int n4 = (int)(n >> 2);
    int blocks = (n4 + 255) / 256; if (blocks > 1024) blocks = 1024;
    f32_to_bf16<<<blocks, 256, 0, stream>>>(s, d, n4);
  };
  conv(x,      xb,      8388608);
  conv(a_wih0, a_wih0b, 720896);
  conv(a_whh0, a_whh0b, 65536);
  conv(p_w0,   p_w0b,   1736704);
  conv(f_wih0, f_wih0b, 1048576);
  conv(f_whh0, f_whh0b, 4194304);
  conv(a_wih1, a_wih1b, 1114112);
  conv(a_whh1, a_whh1b, 65536);
  conv(p_w1,   p_w1b,   1835008);
  conv(f_wih1, f_wih1b, 4194304);
  conv(f_whh1, f_whh1b, 4194304);

  alstm_persistent<<<G_BLOCKS, 256, 0, stream>>>(
      xb, out,
      a_wih0b, a_whh0b, a_bih0, a_bhh0, p_w0b, p_b0, f_wih0b, f_whh0b, f_b0,
      a_wih1b, a_whh1b, a_bih1, a_bhh1, p_w1b, p_b1, f_wih1b, f_whh1b, f_b1,
      a0c, a1c, f0c, f1c, a0xA, a0xB, a1xA, a1xB, f0x, f1x,
      xh0, hh0, xh1, hh1, pbuf, fcnt, bar);
}

// Round 6
// 57875.134 us; speedup vs baseline: 1.6157x; 1.1943x over previous
//
#include <hip/hip_runtime.h>

// ---------- types & helpers ----------
typedef __bf16 bf16x8 __attribute__((ext_vector_type(8)));
typedef float  f32x4  __attribute__((ext_vector_type(4)));

#define AS __HIP_MEMORY_SCOPE_AGENT

__device__ __forceinline__ float bf2f(unsigned short u) {
  union { unsigned int i; float f; } v; v.i = ((unsigned int)u) << 16; return v.f;
}
__device__ __forceinline__ unsigned short f2bf(float f) {
  union { float f; unsigned int u; } v; v.f = f;
  unsigned int r = v.u + 0x7fffu + ((v.u >> 16) & 1u);
  return (unsigned short)(r >> 16);
}
__device__ __forceinline__ float sigm(float x)   { return 1.f / (1.f + __expf(-x)); }
__device__ __forceinline__ float tanh_f(float x) { return 2.f / (1.f + __expf(-2.f * x)) - 1.f; }

// cached load (weights / immutable data only)
__device__ __forceinline__ bf16x8 ld8(const unsigned short* p) {
  return *reinterpret_cast<const bf16x8*>(p);
}
// coherent (agent-scope) accessors for cross-block mutable buffers: always fresh, no fences.
__device__ __forceinline__ bf16x8 ldc8(const unsigned short* p) {
  const unsigned long long* q = (const unsigned long long*)p;
  union { unsigned long long u[2]; bf16x8 v; } r;
  r.u[0] = __hip_atomic_load(q + 0, __ATOMIC_RELAXED, AS);
  r.u[1] = __hip_atomic_load(q + 1, __ATOMIC_RELAXED, AS);
  return r.v;
}
__device__ __forceinline__ unsigned short ldc_bf(const unsigned short* p) {
  return __hip_atomic_load(p, __ATOMIC_RELAXED, AS);
}
__device__ __forceinline__ void stc_bf(unsigned short* p, unsigned short v) {
  __hip_atomic_store(p, v, __ATOMIC_RELAXED, AS);
}
__device__ __forceinline__ void stc2f(float* p, float a, float b) {
  union { float f[2]; unsigned long long u; } v; v.f[0] = a; v.f[1] = b;
  __hip_atomic_store((unsigned long long*)p, v.u, __ATOMIC_RELAXED, AS);
}
__device__ __forceinline__ void ldc2f(const float* p, float& a, float& b) {
  union { unsigned long long u; float f[2]; } v;
  v.u = __hip_atomic_load((const unsigned long long*)p, __ATOMIC_RELAXED, AS);
  a = v.f[0]; b = v.f[1];
}

// ---------- fp32 -> bf16 bulk convert (weights & x), once per launch ----------
__global__ __launch_bounds__(256) void f32_to_bf16(const float* __restrict__ src,
                                                   unsigned short* __restrict__ dst, int n4) {
  int i = blockIdx.x * blockDim.x + threadIdx.x;
  const int stride = gridDim.x * blockDim.x;
  const float4* s4 = (const float4*)src;
  ushort4* d4 = (ushort4*)dst;
  for (; i < n4; i += stride) {
    float4 v = s4[i];
    ushort4 o;
    o.x = f2bf(v.x); o.y = f2bf(v.y); o.z = f2bf(v.z); o.w = f2bf(v.w);
    d4[i] = o;
  }
}

// ---------- LDS layout: f-cell weight K-quarters resident for all 512 steps ----------
struct SMem {
  unsigned short w1[16 * 64 * 32];  // layer1 quarter (64KB)
  unsigned short w0[10 * 64 * 32];  // layer0 quarter (40KB)
  f32x4 red_a[3][4][64];            // adapt-cell K-reduction scratch (12KB)
};

// ---------- grid barrier (R4-proven single counter; no cache invalidation) ----------
#define G_BLOCKS 256
__device__ __forceinline__ void gbar(unsigned* bar, unsigned target) {
  asm volatile("s_waitcnt vmcnt(0)" ::: "memory");
  __syncthreads();
  if (threadIdx.x == 0) {
    __hip_atomic_fetch_add(bar, 1u, __ATOMIC_RELAXED, AS);
    while (__hip_atomic_load(bar, __ATOMIC_RELAXED, AS) < target) {
      __builtin_amdgcn_s_sleep(2);
    }
  }
  __syncthreads();
  asm volatile("" ::: "memory");
}

// ---------- preload this block's f-cell weight K-quarter into LDS ----------
template<int XK, int HK>
__device__ __forceinline__ void preload(unsigned short* wl,
    const unsigned short* __restrict__ wih, const unsigned short* __restrict__ whh,
    int kq, int jb)
{
  constexpr int XC = XK / 32, CT = (XK + HK) / 32, CQ = CT / 4;
  const int c0 = kq * CQ, j0 = jb * 16;
  for (int it = threadIdx.x; it < CQ * 64; it += 256) {
    const int lc = it >> 6, r = it & 63;          // r = g*16 + jj
    const int g = r >> 4, jj = r & 15;
    const int cg = c0 + lc;
    const unsigned short* src = (cg < XC)
        ? wih + (size_t)(g * 1024 + j0 + jj) * XK + cg * 32
        : whh + (size_t)(g * 1024 + j0 + jj) * HK + (cg - XC) * 32;
    ulonglong2* d = (ulonglong2*)(wl + (size_t)it * 32);
    const ulonglong2* s = (const ulonglong2*)src;
    d[0] = s[0]; d[1] = s[1]; d[2] = s[2]; d[3] = s[3];
  }
}

// ---------- stage: standard LSTM cell (adapt). 32 blocks x 4 waves (K-quarters) ----------
template<int C>
__device__ __forceinline__ void seg_quarter(f32x4 acc[4],
    const unsigned short* __restrict__ a, int astride,
    const unsigned short* __restrict__ w, int wstride,
    int m0, int j0, int quad, int col, int kq)
{
  constexpr int CQ = C / 4;
  const unsigned short* ar = a + (size_t)(m0 + col) * astride + quad * 8 + kq * CQ * 32;
  const unsigned short* wr = w + quad * 8 + kq * CQ * 32;
#pragma unroll
  for (int c = 0; c < CQ; c++) {
    bf16x8 af = ldc8(ar + c * 32);
#pragma unroll
    for (int g = 0; g < 4; g++) {
      acc[g] = __builtin_amdgcn_mfma_f32_16x16x32_bf16(
          af, ld8(wr + (size_t)(g * 128 + j0 + col) * wstride + c * 32),
          acc[g], 0, 0, 0);
    }
  }
}

template<int C0, int C1, int C2, int C3>
__device__ __forceinline__ void st_adapt(SMem& sm, int rel,
    const unsigned short* __restrict__ a0, int as0, const unsigned short* __restrict__ w0, int ws0,
    const unsigned short* __restrict__ a1, int as1, const unsigned short* __restrict__ w1, int ws1,
    const unsigned short* __restrict__ a2, int as2, const unsigned short* __restrict__ w2, int ws2,
    const unsigned short* __restrict__ a3, int as3, const unsigned short* __restrict__ w3, int ws3,
    const float* __restrict__ bih, const float* __restrict__ bhh,
    float* __restrict__ cbuf, unsigned short* __restrict__ hbuf)
{
  const int tid = threadIdx.x;
  const int kq = tid >> 6, lane = tid & 63;
  const int quad = lane >> 4, col = lane & 15;
  const int j0 = (rel & 7) * 16, m0 = (rel >> 3) * 16;

  f32x4 acc[4] = {};
  seg_quarter<C0>(acc, a0, as0, w0, ws0, m0, j0, quad, col, kq);
  seg_quarter<C1>(acc, a1, as1, w1, ws1, m0, j0, quad, col, kq);
  seg_quarter<C2>(acc, a2, as2, w2, ws2, m0, j0, quad, col, kq);
  seg_quarter<C3>(acc, a3, as3, w3, ws3, m0, j0, quad, col, kq);

  if (kq) {
#pragma unroll
    for (int g = 0; g < 4; g++) sm.red_a[kq - 1][g][lane] = acc[g];
  }
  __syncthreads();
  if (kq == 0) {
#pragma unroll
    for (int p = 0; p < 3; p++)
#pragma unroll
      for (int g = 0; g < 4; g++) acc[g] += sm.red_a[p][g][lane];

    const int j = j0 + col;
    const float b0 = bih[j]       + bhh[j];
    const float b1 = bih[128 + j] + bhh[128 + j];
    const float b2 = bih[256 + j] + bhh[256 + j];
    const float b3 = bih[384 + j] + bhh[384 + j];
#pragma unroll
    for (int r = 0; r < 4; r++) {
      const int m = m0 + quad * 4 + r;
      const float i_ = sigm(acc[0][r] + b0);
      const float f_ = sigm(acc[1][r] + b1);
      const float g_ = tanh_f(acc[2][r] + b2);
      const float o_ = sigm(acc[3][r] + b3);
      const int idx = m * 128 + j;
      const float c2 = f_ * cbuf[idx] + i_ * g_;   // block-private, cached
      cbuf[idx] = c2;
      stc_bf(&hbuf[idx], f2bf(o_ * tanh_f(c2)));   // cross-block -> coherent
    }
  }
  __syncthreads();  // protect red_a reuse
}

// ---------- stage: x-hat / h-hat production. N/64 blocks x 4 waves ----------
__device__ __forceinline__ void st_policy(int blk,
    const unsigned short* __restrict__ A,
    const unsigned short* __restrict__ pw, const float* __restrict__ pb,
    const unsigned short* __restrict__ xsrc, int xn,
    const unsigned short* __restrict__ hsrc, int hn,
    unsigned short* __restrict__ xhat, unsigned short* __restrict__ hhat)
{
  const int wave = threadIdx.x >> 6, lane = threadIdx.x & 63;
  const int quad = lane >> 4, col = lane & 15;
  const int m0 = wave * 16, n0 = blk * 64;

  f32x4 acc[4] = {};
  const unsigned short* arow = A + (size_t)(m0 + col) * 128 + quad * 8;
  bf16x8 afs[4];
#pragma unroll
  for (int c = 0; c < 4; c++) afs[c] = ldc8(arow + c * 32);
#pragma unroll
  for (int c = 0; c < 4; c++) {
#pragma unroll
    for (int s = 0; s < 4; s++) {
      acc[s] = __builtin_amdgcn_mfma_f32_16x16x32_bf16(
          afs[c], ld8(pw + (size_t)(n0 + s * 16 + col) * 128 + quad * 8 + c * 32),
          acc[s], 0, 0, 0);
    }
  }
#pragma unroll
  for (int s = 0; s < 4; s++) {
    const int n = n0 + s * 16 + col;
    const float bias = pb[n];
#pragma unroll
    for (int r = 0; r < 4; r++) {
      const int m = m0 + quad * 4 + r;
      const float v = acc[s][r] + bias;
      if (n < xn) {
        stc_bf(&xhat[m * xn + n], f2bf(v * bf2f(ldc_bf(&xsrc[m * xn + n]))));
      } else {
        stc_bf(&hhat[m * hn + (n - xn)], f2bf(v * bf2f(ldc_bf(&hsrc[m * hn + (n - xn)]))));
      }
    }
  }
}

// ---------- stage: adaptive LSTM f-cell. 256 blocks = 64 j x 4 K-quarters ----------
// Combined-scale partials: every block computes its own pg0/pg1 policy slices and
// publishes ONE pre-scaled f32x4 per gate; collector (kq0) adds fb term + epilogue.
template<int XK, int HK>
__device__ __forceinline__ void st_fcell(SMem& sm, int jb, int kq,
    const unsigned short* __restrict__ xhat, const unsigned short* __restrict__ hhat,
    const float* __restrict__ fb, const unsigned short* __restrict__ ax,
    const unsigned short* __restrict__ pw, const float* __restrict__ pb,
    int ig_off, int hg_off, int ab_off,
    float* __restrict__ cbuf, unsigned short* __restrict__ hbuf, float* __restrict__ outp,
    float* __restrict__ pbuf, unsigned* fcnt, unsigned ftarget)
{
  constexpr int XC = XK / 32, CT = (XK + HK) / 32, CQ = CT / 4;
  const int tid = threadIdx.x;
  const int wave = tid >> 6, lane = tid & 63;
  const int quad = lane >> 4, col = lane & 15;
  const int m0 = wave * 16, j0 = jb * 16, c0 = kq * CQ;
  const unsigned short* wl = (XK == 1024) ? sm.w1 : sm.w0;

  // 1) issue ax loads (oldest)
  bf16x8 axr[4];
  {
    const unsigned short* ar = ax + (size_t)(m0 + col) * 128 + quad * 8;
#pragma unroll
    for (int c = 0; c < 4; c++) axr[c] = ldc8(ar + c * 32);
  }
  // 2) issue ALL activation loads for this K-quarter (deep pipeline)
  bf16x8 act[CQ];
#pragma unroll
  for (int lc = 0; lc < CQ; lc++) {
    const int cg = c0 + lc;
    act[lc] = (cg < XC)
        ? ldc8(xhat + (size_t)(m0 + col) * XK + cg * 32 + quad * 8)
        : ldc8(hhat + (size_t)(m0 + col) * HK + (cg - XC) * 32 + quad * 8);
  }
  // 3) policy gate-scale slices (pw L2-resident); collector also needs ab set
  f32x4 pg0[4] = {}, pg1[4] = {}, pg2[4] = {};
#pragma unroll
  for (int c = 0; c < 4; c++) {
#pragma unroll
    for (int g = 0; g < 4; g++) {
      pg0[g] = __builtin_amdgcn_mfma_f32_16x16x32_bf16(
          axr[c], ld8(pw + (size_t)(ig_off + g * 1024 + j0 + col) * 128 + quad * 8 + c * 32), pg0[g], 0, 0, 0);
      pg1[g] = __builtin_amdgcn_mfma_f32_16x16x32_bf16(
          axr[c], ld8(pw + (size_t)(hg_off + g * 1024 + j0 + col) * 128 + quad * 8 + c * 32), pg1[g], 0, 0, 0);
    }
    if (kq == 0) {
#pragma unroll
      for (int g = 0; g < 4; g++) {
        pg2[g] = __builtin_amdgcn_mfma_f32_16x16x32_bf16(
            axr[c], ld8(pw + (size_t)(ab_off + g * 1024 + j0 + col) * 128 + quad * 8 + c * 32), pg2[g], 0, 0, 0);
      }
    }
  }
  // 4) main GEMM quarter from LDS weights (staged activations)
  f32x4 ai[4] = {}, ah[4] = {};
#pragma unroll
  for (int lc = 0; lc < CQ; lc++) {
    const int cg = c0 + lc;
    const unsigned short* wr = wl + lc * 2048 + col * 32 + quad * 8;
    if (cg < XC) {
#pragma unroll
      for (int g = 0; g < 4; g++)
        ai[g] = __builtin_amdgcn_mfma_f32_16x16x32_bf16(act[lc], ld8(wr + g * 512), ai[g], 0, 0, 0);
    } else {
#pragma unroll
      for (int g = 0; g < 4; g++)
        ah[g] = __builtin_amdgcn_mfma_f32_16x16x32_bf16(act[lc], ld8(wr + g * 512), ah[g], 0, 0, 0);
    }
  }
  // 5) combine with scales (identical across kq -> linear in partials)
  const int j = j0 + col;
  float pbi[4], pbh[4];
#pragma unroll
  for (int g = 0; g < 4; g++) {
    pbi[g] = pb[ig_off + g * 1024 + j];
    pbh[g] = pb[hg_off + g * 1024 + j];
  }
  f32x4 comb[4];
#pragma unroll
  for (int g = 0; g < 4; g++)
#pragma unroll
    for (int r = 0; r < 4; r++)
      comb[g][r] = ai[g][r] * (pg0[g][r] + pbi[g]) + ah[g][r] * (pg1[g][r] + pbh[g]);

  if (kq) {
#pragma unroll
    for (int g = 0; g < 4; g++) {
      float* pp = pbuf + ((size_t)(((kq - 1) * 64 + jb) * 4 + wave) * 4 + g) * 256 + lane * 4;
      stc2f(pp, comb[g][0], comb[g][1]); stc2f(pp + 2, comb[g][2], comb[g][3]);
    }
    asm volatile("s_waitcnt vmcnt(0)" ::: "memory");
    __syncthreads();
    if (tid == 0) __hip_atomic_fetch_add(&fcnt[jb * 8], 1u, __ATOMIC_RELAXED, AS);
    return;
  }

  // collector: wait 3 siblings, fixed-order combine, epilogue
  if (tid == 0) {
    while (__hip_atomic_load(&fcnt[jb * 8], __ATOMIC_RELAXED, AS) < ftarget)
      __builtin_amdgcn_s_sleep(1);
  }
  __syncthreads();
  asm volatile("" ::: "memory");
#pragma unroll
  for (int kk = 0; kk < 3; kk++) {
#pragma unroll
    for (int g = 0; g < 4; g++) {
      const float* pp = pbuf + ((size_t)((kk * 64 + jb) * 4 + wave) * 4 + g) * 256 + lane * 4;
      float a, b, c, d;
      ldc2f(pp, a, b); ldc2f(pp + 2, c, d);
      comb[g][0] += a; comb[g][1] += b; comb[g][2] += c; comb[g][3] += d;
    }
  }
  float pba[4], fbv[4];
#pragma unroll
  for (int g = 0; g < 4; g++) {
    pba[g] = pb[ab_off + g * 1024 + j];
    fbv[g] = fb[g * 1024 + j];
  }
#pragma unroll
  for (int r = 0; r < 4; r++) {
    const int m = m0 + quad * 4 + r;
    float gate[4];
#pragma unroll
    for (int g = 0; g < 4; g++)
      gate[g] = comb[g][r] + fbv[g] * (pg2[g][r] + pba[g]);
    const float i_ = sigm(gate[0]);
    const float f_ = sigm(gate[1]);
    const float g_ = tanh_f(gate[2]);
    const float o_ = sigm(gate[3]);
    const int idx = m * 1024 + j;
    const float c2 = f_ * cbuf[idx] + i_ * g_;   // block-private, cached
    cbuf[idx] = c2;
    const float h = o_ * tanh_f(c2);
    stc_bf(&hbuf[idx], f2bf(h));                 // cross-block -> coherent
    if (outp) __builtin_nontemporal_store(h, &outp[idx]);
  }
}

// ---------- persistent kernel: 3 barrier slots per step ----------
// A:{fcell0}  B':{adapt1 -> flag -> policy1 || adapt0(t+1)}  C':{fcell1 ; policy0(t+1) on kq3}
__global__ __launch_bounds__(256, 1) void alstm_persistent(
    const unsigned short* __restrict__ xb, float* __restrict__ out,
    const unsigned short* __restrict__ a_wih0b, const unsigned short* __restrict__ a_whh0b,
    const float* __restrict__ a_bih0, const float* __restrict__ a_bhh0,
    const unsigned short* __restrict__ p_w0b, const float* __restrict__ p_b0,
    const unsigned short* __restrict__ f_wih0b, const unsigned short* __restrict__ f_whh0b,
    const float* __restrict__ f_b0,
    const unsigned short* __restrict__ a_wih1b, const unsigned short* __restrict__ a_whh1b,
    const float* __restrict__ a_bih1, const float* __restrict__ a_bhh1,
    const unsigned short* __restrict__ p_w1b, const float* __restrict__ p_b1,
    const unsigned short* __restrict__ f_wih1b, const unsigned short* __restrict__ f_whh1b,
    const float* __restrict__ f_b1,
    float* a0c, float* a1c, float* f0c, float* f1c,
    unsigned short* a0xA, unsigned short* a0xB,
    unsigned short* a1xA, unsigned short* a1xB,
    unsigned short* f0x, unsigned short* f1x,
    unsigned short* xh0, unsigned short* hh0,
    unsigned short* xh1, unsigned short* hh1,
    float* pbuf, unsigned* fcnt, unsigned* bar, unsigned* abar)
{
  __shared__ SMem sm;
  const int blk = blockIdx.x;
  const int jb = blk & 63, kq = blk >> 6;
  const int tid = threadIdx.x;
  unsigned ep = 0, fc_ep = 0;

  // one-time: stage this block's f-cell weight quarters into LDS
  preload<1024, 1024>(sm.w1, f_wih1b, f_whh1b, kq, jb);
  preload<256,  1024>(sm.w0, f_wih0b, f_whh0b, kq, jb);
  __syncthreads();

  // prologue: adapt0(0) then policy0(0)
  if (blk >= 32 && blk < 64)
    st_adapt<8, 32, 4, 4>(sm, blk - 32,
        xb, 256, a_wih0b, 1408,
        f0x, 1024, a_wih0b + 256, 1408,
        a1xB, 128, a_wih0b + 1280, 1408,
        a0xB, 128, a_whh0b, 128,
        a_bih0, a_bhh0, a0c, a0xA);
  gbar(bar, ++ep * (unsigned)G_BLOCKS);
  if (kq == 3 && jb < 20)
    st_policy(jb, a0xA, p_w0b, p_b0, xb, 256, f0x, 1024, xh0, hh0);
  gbar(bar, ++ep * (unsigned)G_BLOCKS);

#pragma unroll 1
  for (int t = 0; t < 512; t++) {
    const unsigned short* xt1 = xb + (size_t)(t + 1) * 64 * 256;
    unsigned short* a0x_cur  = (t & 1) ? a0xB : a0xA;
    unsigned short* a0x_nxt  = (t & 1) ? a0xA : a0xB;
    unsigned short* a1x_cur  = (t & 1) ? a1xB : a1xA;
    unsigned short* a1x_prev = (t & 1) ? a1xA : a1xB;
    const bool more = (t + 1 < 512);

    // slot A: f-cell 0 (all blocks)
    fc_ep++;
    st_fcell<256, 1024>(sm, jb, kq, xh0, hh0, f_b0,
                        a0x_cur, p_w0b, p_b0, 1280, 5376, 9472,
                        f0c, f0x, (float*)nullptr, pbuf, fcnt, 3u * fc_ep);
    gbar(bar, ++ep * (unsigned)G_BLOCKS);

    // slot B': adapt1 -> flag -> { policy1 || adapt0(t+1) }
    if (blk < 32) {
      st_adapt<32, 32, 4, 4>(sm, blk,
          f0x, 1024, a_wih1b, 2176,
          f1x, 1024, a_wih1b + 1024, 2176,
          a0x_cur, 128, a_wih1b + 2048, 2176,
          a1x_prev, 128, a_whh1b, 128,
          a_bih1, a_bhh1, a1c, a1x_cur);
      asm volatile("s_waitcnt vmcnt(0)" ::: "memory");
      __syncthreads();
      if (tid == 0) __hip_atomic_fetch_add(abar, 1u, __ATOMIC_RELAXED, AS);
    } else if (blk < 96) {
      if (tid == 0) {
        while (__hip_atomic_load(abar, __ATOMIC_RELAXED, AS) < 32u * (unsigned)(t + 1))
          __builtin_amdgcn_s_sleep(2);
      }
      __syncthreads();
      asm volatile("" ::: "memory");
      if (blk < 64)
        st_policy(blk - 32, a1x_cur, p_w1b, p_b1, f0x, 1024, f1x, 1024, xh1, hh1);
      else if (more)
        st_adapt<8, 32, 4, 4>(sm, blk - 64,
            xt1, 256, a_wih0b, 1408,
            f0x, 1024, a_wih0b + 256, 1408,
            a1x_cur, 128, a_wih0b + 1280, 1408,
            a0x_cur, 128, a_whh0b, 128,
            a_bih0, a_bhh0, a0c, a0x_nxt);
    }
    gbar(bar, ++ep * (unsigned)G_BLOCKS);

    // slot C': f-cell 1 (all blocks); kq3/jb<20 siblings then run policy0(t+1)
    fc_ep++;
    st_fcell<1024, 1024>(sm, jb, kq, xh1, hh1, f_b1,
                         a1x_cur, p_w1b, p_b1, 2048, 6144, 10240,
                         f1c, f1x, out + (size_t)t * 64 * 1024, pbuf, fcnt, 3u * fc_ep);
    if (kq == 3 && jb < 20 && more)
      st_policy(jb, a0x_nxt, p_w0b, p_b0, xt1, 256, f0x, 1024, xh0, hh0);
    gbar(bar, ++ep * (unsigned)G_BLOCKS);
  }
}

extern "C" void kernel_launch(void* const* d_in, const int* in_sizes, int n_in,
                              void* d_out, int out_size, void* d_ws, size_t ws_size,
                              hipStream_t stream)
{
  const float* x      = (const float*)d_in[0];
  const float* a_wih0 = (const float*)d_in[1];
  const float* a_whh0 = (const float*)d_in[2];
  const float* a_bih0 = (const float*)d_in[3];
  const float* a_bhh0 = (const float*)d_in[4];
  const float* p_w0   = (const float*)d_in[5];
  const float* p_b0   = (const float*)d_in[6];
  const float* f_wih0 = (const float*)d_in[7];
  const float* f_whh0 = (const float*)d_in[8];
  const float* f_b0   = (const float*)d_in[9];
  const float* a_wih1 = (const float*)d_in[10];
  const float* a_whh1 = (const float*)d_in[11];
  const float* a_bih1 = (const float*)d_in[12];
  const float* a_bhh1 = (const float*)d_in[13];
  const float* p_w1   = (const float*)d_in[14];
  const float* p_b1   = (const float*)d_in[15];
  const float* f_wih1 = (const float*)d_in[16];
  const float* f_whh1 = (const float*)d_in[17];
  const float* f_b1   = (const float*)d_in[18];
  float* out = (float*)d_out;

  // ---- workspace carve-up (256B-aligned cursor) ----
  char* p = (char*)d_ws;
  auto alloc = [&](size_t bytes) { char* r = p; p += (bytes + 255) & ~(size_t)255; return r; };

  // zeroed each launch: sync counters + recurrent state
  unsigned* bar  = (unsigned*)alloc(256);
  unsigned* abar = (unsigned*)alloc(256);
  unsigned* fcnt = (unsigned*)alloc(64 * 8 * 4);    // per-j flags, 32B apart
  float* a0c = (float*)alloc(64 * 128 * 4);
  float* a1c = (float*)alloc(64 * 128 * 4);
  float* f0c = (float*)alloc(64 * 1024 * 4);
  float* f1c = (float*)alloc(64 * 1024 * 4);
  unsigned short* a0xA = (unsigned short*)alloc(64 * 128 * 2);
  unsigned short* a0xB = (unsigned short*)alloc(64 * 128 * 2);
  unsigned short* a1xA = (unsigned short*)alloc(64 * 128 * 2);
  unsigned short* a1xB = (unsigned short*)alloc(64 * 128 * 2);
  unsigned short* f0x  = (unsigned short*)alloc(64 * 1024 * 2);
  unsigned short* f1x  = (unsigned short*)alloc(64 * 1024 * 2);
  const size_t zero_bytes = (size_t)(p - (char*)d_ws);

  // per-step scratch (fully written before read each step)
  unsigned short* xh0 = (unsigned short*)alloc(64 * 256 * 2);
  unsigned short* hh0 = (unsigned short*)alloc(64 * 1024 * 2);
  unsigned short* xh1 = (unsigned short*)alloc(64 * 1024 * 2);
  unsigned short* hh1 = (unsigned short*)alloc(64 * 1024 * 2);
  float* pbuf = (float*)alloc((size_t)3 * 64 * 4 * 4 * 256 * 4);  // 3MB combined partials

  // bf16 conversions of x + weights
  unsigned short* xb      = (unsigned short*)alloc((size_t)8388608 * 2);
  unsigned short* a_wih0b = (unsigned short*)alloc((size_t)720896 * 2);
  unsigned short* a_whh0b = (unsigned short*)alloc((size_t)65536 * 2);
  unsigned short* p_w0b   = (unsigned short*)alloc((size_t)1736704 * 2);
  unsigned short* f_wih0b = (unsigned short*)alloc((size_t)1048576 * 2);
  unsigned short* f_whh0b = (unsigned short*)alloc((size_t)4194304 * 2);
  unsigned short* a_wih1b = (unsigned short*)alloc((size_t)1114112 * 2);
  unsigned short* a_whh1b = (unsigned short*)alloc((size_t)65536 * 2);
  unsigned short* p_w1b   = (unsigned short*)alloc((size_t)1835008 * 2);
  unsigned short* f_wih1b = (unsigned short*)alloc((size_t)4194304 * 2);
  unsigned short* f_whh1b = (unsigned short*)alloc((size_t)4194304 * 2);

  hipMemsetAsync(d_ws, 0, zero_bytes, stream);

  auto conv = [&](const float* s, unsigned short* d, size_t n) {
    int n4 = (int)(n >> 2);
    int blocks = (n4 + 255) / 256; if (blocks > 1024) blocks = 1024;
    f32_to_bf16<<<blocks, 256, 0, stream>>>(s, d, n4);
  };
  conv(x,      xb,      8388608);
  conv(a_wih0, a_wih0b, 720896);
  conv(a_whh0, a_whh0b, 65536);
  conv(p_w0,   p_w0b,   1736704);
  conv(f_wih0, f_wih0b, 1048576);
  conv(f_whh0, f_whh0b, 4194304);
  conv(a_wih1, a_wih1b, 1114112);
  conv(a_whh1, a_whh1b, 65536);
  conv(p_w1,   p_w1b,   1835008);
  conv(f_wih1, f_wih1b, 4194304);
  conv(f_whh1, f_whh1b, 4194304);

  alstm_persistent<<<G_BLOCKS, 256, 0, stream>>>(
      xb, out,
      a_wih0b, a_whh0b, a_bih0, a_bhh0, p_w0b, p_b0, f_wih0b, f_whh0b, f_b0,
      a_wih1b, a_whh1b, a_bih1, a_bhh1, p_w1b, p_b1, f_wih1b, f_whh1b, f_b1,
      a0c, a1c, f0c, f1c, a0xA, a0xB, a1xA, a1xB, f0x, f1x,
      xh0, hh0, xh1, hh1, pbuf, fcnt, bar, abar);
}